// Round 1
// baseline (1243.061 us; speedup 1.0000x reference)
//
#include <hip/hip_runtime.h>

constexpr int B = 4, H = 96, W = 96, HW = H * W;
constexpr int NPIX = B * HW;   // 36864
constexpr int KOFF = 18;       // 2*K offset channels

__device__ __forceinline__ int iclamp(int v, int lo, int hi) {
  return v < lo ? lo : (v > hi ? hi : v);
}

// in: (Oc, C, 3, 3) -> out: (C, 9, Oc)   (so inner o-loop is contiguous + uniform)
__global__ void transpose_w_kernel(const float* __restrict__ in, float* __restrict__ out,
                                   int Oc, int C) {
  int i = blockIdx.x * blockDim.x + threadIdx.x;
  int total = Oc * C * 9;
  if (i >= total) return;
  int k = i % 9;
  int c = (i / 9) % C;
  int o = i / (9 * C);
  out[(c * 9 + k) * Oc + o] = in[i];
}

// 3x3 conv, pad 1: x (B,C,H,W) -> out (B,18,H,W); wt is (C,9,18)
template <int C, int OCT>
__global__ void offset_conv_kernel(const float* __restrict__ x, const float* __restrict__ wt,
                                   const float* __restrict__ bo, float* __restrict__ out) {
  int pix = blockIdx.x * blockDim.x + threadIdx.x;   // b*HW + h*W + w  (grid exact)
  int ocbase = blockIdx.y * OCT;
  int w = pix % W;
  int h = (pix / W) % H;
  int b = pix / HW;
  float acc[OCT];
#pragma unroll
  for (int i = 0; i < OCT; ++i) acc[i] = bo[ocbase + i];
  const float* xb = x + b * C * HW;
  for (int c = 0; c < C; ++c) {
    const float* xc = xb + c * HW;
#pragma unroll
    for (int ky = 0; ky < 3; ++ky) {
      int yy = h + ky - 1;
      bool yv = (yy >= 0) & (yy < H);
#pragma unroll
      for (int kx = 0; kx < 3; ++kx) {
        int xx = w + kx - 1;
        bool v = yv & (xx >= 0) & (xx < W);
        float val = v ? xc[yy * W + xx] : 0.0f;
        const float* wp = wt + (c * 9 + ky * 3 + kx) * KOFF + ocbase;
#pragma unroll
        for (int i = 0; i < OCT; ++i) acc[i] = fmaf(val, wp[i], acc[i]);
      }
    }
  }
  float* ob = out + b * KOFF * HW + h * W + w;
#pragma unroll
  for (int i = 0; i < OCT; ++i) ob[(ocbase + i) * HW] = acc[i];
}

// deformable conv: x (B,C,H,W), off (B,18,H,W), wt (C,9,O), out (B,O,H,W)
template <int C, int O, int OT>
__global__ void deform_conv_kernel(const float* __restrict__ x, const float* __restrict__ off,
                                   const float* __restrict__ wt, const float* __restrict__ bd,
                                   float* __restrict__ out) {
  int pix = blockIdx.x * blockDim.x + threadIdx.x;
  int obase = blockIdx.y * OT;
  int w = pix % W;
  int h = (pix / W) % H;
  int b = pix / HW;
  float acc[OT];
#pragma unroll
  for (int i = 0; i < OT; ++i) acc[i] = bd[obase + i];
  const float* offp = off + b * KOFF * HW + h * W + w;
  const float* xb = x + b * C * HW;
#pragma unroll 1
  for (int k = 0; k < 9; ++k) {
    float dy = offp[(2 * k) * HW];
    float dx = offp[(2 * k + 1) * HW];
    float py = dy + (float)(k / 3 + h - 1);
    float px = dx + (float)(k % 3 + w - 1);
    float fy = floorf(py);
    float fx = floorf(px);
    float wy = py - fy;
    float wx = px - fx;
    int y0 = (int)fy, x0 = (int)fx;
    int y1 = y0 + 1, x1 = x0 + 1;
    bool vy0 = (y0 >= 0) & (y0 < H);
    bool vy1 = (y1 >= 0) & (y1 < H);
    bool vx0 = (x0 >= 0) & (x0 < W);
    bool vx1 = (x1 >= 0) & (x1 < W);
    int r0 = iclamp(y0, 0, H - 1) * W;
    int r1 = iclamp(y1, 0, H - 1) * W;
    int c0 = iclamp(x0, 0, W - 1);
    int c1 = iclamp(x1, 0, W - 1);
    float w00 = (1.f - wy) * (1.f - wx) * ((vy0 & vx0) ? 1.f : 0.f);
    float w01 = (1.f - wy) * wx * ((vy0 & vx1) ? 1.f : 0.f);
    float w10 = wy * (1.f - wx) * ((vy1 & vx0) ? 1.f : 0.f);
    float w11 = wy * wx * ((vy1 & vx1) ? 1.f : 0.f);
    int i00 = r0 + c0, i01 = r0 + c1, i10 = r1 + c0, i11 = r1 + c1;
    for (int c = 0; c < C; ++c) {
      const float* xc = xb + c * HW;
      float samp = xc[i00] * w00 + xc[i01] * w01 + xc[i10] * w10 + xc[i11] * w11;
      const float* wp = wt + (c * 9 + k) * O + obase;
#pragma unroll
      for (int i = 0; i < OT; ++i) acc[i] = fmaf(samp, wp[i], acc[i]);
    }
  }
  float* ob = out + b * O * HW + h * W + w;
#pragma unroll
  for (int i = 0; i < OT; ++i) ob[(obase + i) * HW] = acc[i];
}

static inline void launch_transpose(const float* in, float* out, int Oc, int C,
                                    hipStream_t stream) {
  int total = Oc * C * 9;
  int blocks = (total + 255) / 256;
  hipLaunchKernelGGL(transpose_w_kernel, dim3(blocks), dim3(256), 0, stream, in, out, Oc, C);
}

extern "C" void kernel_launch(void* const* d_in, const int* in_sizes, int n_in,
                              void* d_out, int out_size, void* d_ws, size_t ws_size,
                              hipStream_t stream) {
  const float* x1  = (const float*)d_in[0];
  const float* y   = (const float*)d_in[1];
  const float* wo1 = (const float*)d_in[2];
  const float* bo1 = (const float*)d_in[3];
  const float* wd1 = (const float*)d_in[4];
  const float* bd1 = (const float*)d_in[5];
  const float* wo2 = (const float*)d_in[6];
  const float* bo2 = (const float*)d_in[7];
  const float* wd2 = (const float*)d_in[8];
  const float* bd2 = (const float*)d_in[9];
  const float* wo3 = (const float*)d_in[10];
  const float* bo3 = (const float*)d_in[11];
  const float* wd3 = (const float*)d_in[12];
  const float* bd3 = (const float*)d_in[13];
  float* out = (float*)d_out;

  // workspace partition (floats)
  float* ws = (float*)d_ws;
  float* wtO1 = ws;                      // 18*64*9  = 10368
  float* wtD1 = wtO1 + 18 * 64 * 9;      // 96*64*9  = 55296
  float* wtO2 = wtD1 + 96 * 64 * 9;      // 18*96*9  = 15552
  float* wtD2 = wtO2 + 18 * 96 * 9;      // 96*96*9  = 82944
  float* wtO3 = wtD2 + 96 * 96 * 9;      // 18*96*9  = 15552
  float* wtD3 = wtO3 + 18 * 96 * 9;      // 64*96*9  = 55296
  float* offs = wtD3 + 64 * 96 * 9;      // 4*18*HW  = 663552
  float* h1   = offs + B * KOFF * HW;    // 4*96*HW  = 3538944
  float* h2   = h1 + B * 96 * HW;        // 4*96*HW  = 3538944

  launch_transpose(wo1, wtO1, 18, 64, stream);
  launch_transpose(wd1, wtD1, 96, 64, stream);
  launch_transpose(wo2, wtO2, 18, 96, stream);
  launch_transpose(wd2, wtD2, 96, 96, stream);
  launch_transpose(wo3, wtO3, 18, 96, stream);
  launch_transpose(wd3, wtD3, 64, 96, stream);

  dim3 blk(256);
  dim3 gconv(NPIX / 256, 3);   // 18 oc = 3 slices of 6
  dim3 gdef96(NPIX / 256, 4);  // 96 o  = 4 slices of 24
  dim3 gdef64(NPIX / 256, 4);  // 64 o  = 4 slices of 16

  // stage 1: offsets from y, deform x1 -> h1 (C=64 -> O=96)
  hipLaunchKernelGGL((offset_conv_kernel<64, 6>), gconv, blk, 0, stream, y, wtO1, bo1, offs);
  hipLaunchKernelGGL((deform_conv_kernel<64, 96, 24>), gdef96, blk, 0, stream, x1, offs, wtD1, bd1, h1);

  // stage 2: h1 -> h2 (C=96 -> O=96)
  hipLaunchKernelGGL((offset_conv_kernel<96, 6>), gconv, blk, 0, stream, h1, wtO2, bo2, offs);
  hipLaunchKernelGGL((deform_conv_kernel<96, 96, 24>), gdef96, blk, 0, stream, h1, offs, wtD2, bd2, h2);

  // stage 3: h2 -> out (C=96 -> O=64)
  hipLaunchKernelGGL((offset_conv_kernel<96, 6>), gconv, blk, 0, stream, h2, wtO3, bo3, offs);
  hipLaunchKernelGGL((deform_conv_kernel<96, 64, 16>), gdef64, blk, 0, stream, h2, offs, wtD3, bd3, out);
}

// Round 2
// 565.962 us; speedup vs baseline: 2.1964x; 2.1964x over previous
//
#include <hip/hip_runtime.h>

constexpr int B = 4, H = 96, W = 96, HW = H * W;
constexpr int NPIX = B * HW;   // 36864
constexpr int KOFF = 18;       // 2*K offset channels

typedef _Float16 half8 __attribute__((ext_vector_type(8)));
typedef _Float16 half4 __attribute__((ext_vector_type(4)));
typedef float f32x4 __attribute__((ext_vector_type(4)));

__device__ __forceinline__ int iclamp(int v, int lo, int hi) {
  return v < lo ? lo : (v > hi ? hi : v);
}

// ---------- weight prep ----------
// fp32: (Oc, C, 3, 3) -> (C*9 + k? ) layout (c*9+k, Oc) for offset conv
__global__ void transpose_w_kernel(const float* __restrict__ in, float* __restrict__ out,
                                   int Oc, int C) {
  int i = blockIdx.x * blockDim.x + threadIdx.x;
  int total = Oc * C * 9;
  if (i >= total) return;
  int k = i % 9;
  int c = (i / 9) % C;
  int o = i / (9 * C);
  out[(c * 9 + k) * Oc + o] = in[i];
}

// fp16 GEMM weights: (O, C, 3, 3) -> [o][kk*C + c]
__global__ void conv_w_gemm_kernel(const float* __restrict__ in, _Float16* __restrict__ out,
                                   int O, int C) {
  int i = blockIdx.x * blockDim.x + threadIdx.x;
  int total = O * C * 9;
  if (i >= total) return;
  int kk = i % 9;
  int c = (i / 9) % C;
  int o = i / (9 * C);
  out[(size_t)o * (C * 9) + kk * C + c] = (_Float16)in[i];
}

// ---------- offset conv (fp32, unchanged from round 1) ----------
template <int C, int OCT>
__global__ void offset_conv_kernel(const float* __restrict__ x, const float* __restrict__ wt,
                                   const float* __restrict__ bo, float* __restrict__ out) {
  int pix = blockIdx.x * blockDim.x + threadIdx.x;
  int ocbase = blockIdx.y * OCT;
  int w = pix % W;
  int h = (pix / W) % H;
  int b = pix / HW;
  float acc[OCT];
#pragma unroll
  for (int i = 0; i < OCT; ++i) acc[i] = bo[ocbase + i];
  const float* xb = x + b * C * HW;
  for (int c = 0; c < C; ++c) {
    const float* xc = xb + c * HW;
#pragma unroll
    for (int ky = 0; ky < 3; ++ky) {
      int yy = h + ky - 1;
      bool yv = (yy >= 0) & (yy < H);
#pragma unroll
      for (int kx = 0; kx < 3; ++kx) {
        int xx = w + kx - 1;
        bool v = yv & (xx >= 0) & (xx < W);
        float val = v ? xc[yy * W + xx] : 0.0f;
        const float* wp = wt + (c * 9 + ky * 3 + kx) * KOFF + ocbase;
#pragma unroll
        for (int i = 0; i < OCT; ++i) acc[i] = fmaf(val, wp[i], acc[i]);
      }
    }
  }
  float* ob = out + b * KOFF * HW + h * W + w;
#pragma unroll
  for (int i = 0; i < OCT; ++i) ob[(ocbase + i) * HW] = acc[i];
}

// ---------- bilinear gather -> fp16 im2col ----------
// thread = (pixel, tap k); writes samp[pix][k*C + c], c = 0..C-1
template <int C>
__global__ void gather_kernel(const float* __restrict__ x, const float* __restrict__ off,
                              _Float16* __restrict__ samp) {
  int pix = blockIdx.x * blockDim.x + threadIdx.x;
  int k = blockIdx.y;
  int w = pix % W;
  int h = (pix / W) % H;
  int b = pix / HW;
  const float* offp = off + (size_t)b * KOFF * HW + h * W + w;
  float dy = offp[(2 * k) * HW];
  float dx = offp[(2 * k + 1) * HW];
  float py = dy + (float)(k / 3 + h - 1);
  float px = dx + (float)(k % 3 + w - 1);
  float fy = floorf(py);
  float fx = floorf(px);
  float wy = py - fy;
  float wx = px - fx;
  int y0 = (int)fy, x0 = (int)fx;
  int y1 = y0 + 1, x1 = x0 + 1;
  bool vy0 = (y0 >= 0) & (y0 < H);
  bool vy1 = (y1 >= 0) & (y1 < H);
  bool vx0 = (x0 >= 0) & (x0 < W);
  bool vx1 = (x1 >= 0) & (x1 < W);
  int r0 = iclamp(y0, 0, H - 1) * W;
  int r1 = iclamp(y1, 0, H - 1) * W;
  int c0i = iclamp(x0, 0, W - 1);
  int c1i = iclamp(x1, 0, W - 1);
  float w00 = (1.f - wy) * (1.f - wx) * ((vy0 & vx0) ? 1.f : 0.f);
  float w01 = (1.f - wy) * wx * ((vy0 & vx1) ? 1.f : 0.f);
  float w10 = wy * (1.f - wx) * ((vy1 & vx0) ? 1.f : 0.f);
  float w11 = wy * wx * ((vy1 & vx1) ? 1.f : 0.f);
  int i00 = r0 + c0i, i01 = r0 + c1i, i10 = r1 + c0i, i11 = r1 + c1i;
  const float* xb = x + (size_t)b * C * HW;
  _Float16* sp = samp + (size_t)pix * (9 * C) + k * C;
  for (int cc = 0; cc < C; cc += 4) {
    half4 hv;
#pragma unroll
    for (int u = 0; u < 4; ++u) {
      const float* xc = xb + (cc + u) * HW;
      float s = xc[i00] * w00 + xc[i01] * w01 + xc[i10] * w10 + xc[i11] * w11;
      hv[u] = (_Float16)s;
    }
    *(half4*)(sp + cc) = hv;
  }
}

// ---------- MFMA GEMM: out[n, o] = bias[o] + sum_ck samp[n, ck] * W[o][ck] ----------
// wave (block of 64) owns 64 pixels x all O. samp: [n][CK] fp16, wt: [o][CK] fp16.
template <int CK, int O>
__global__ __launch_bounds__(64)
void gemm_kernel(const _Float16* __restrict__ samp, const _Float16* __restrict__ wt,
                 const float* __restrict__ bd, float* __restrict__ out) {
  constexpr int NO = O / 16;
  int lane = threadIdx.x;
  int n0 = blockIdx.x * 64;
  int row = lane & 15;    // A n-row within tile / B o-row / D o-col
  int kgrp = lane >> 4;   // k-chunk for A/B, n-row-chunk for D
  f32x4 acc[4][NO];
#pragma unroll
  for (int j = 0; j < NO; ++j) {
    float bv = bd[j * 16 + row];
#pragma unroll
    for (int t = 0; t < 4; ++t) acc[t][j] = {bv, bv, bv, bv};
  }
  for (int ks = 0; ks < CK / 32; ++ks) {
    int kb = ks * 32 + kgrp * 8;
    half8 a[4];
#pragma unroll
    for (int t = 0; t < 4; ++t)
      a[t] = *(const half8*)(samp + (size_t)(n0 + t * 16 + row) * CK + kb);
    half8 bfr[NO];
#pragma unroll
    for (int j = 0; j < NO; ++j)
      bfr[j] = *(const half8*)(wt + (size_t)(j * 16 + row) * CK + kb);
#pragma unroll
    for (int t = 0; t < 4; ++t)
#pragma unroll
      for (int j = 0; j < NO; ++j)
        acc[t][j] = __builtin_amdgcn_mfma_f32_16x16x32_f16(a[t], bfr[j], acc[t][j], 0, 0, 0);
  }
#pragma unroll
  for (int t = 0; t < 4; ++t) {
#pragma unroll
    for (int j = 0; j < NO; ++j) {
#pragma unroll
      for (int r = 0; r < 4; ++r) {
        int n = n0 + t * 16 + kgrp * 4 + r;
        int b = n / HW;
        int hw = n - b * HW;
        out[((size_t)b * O + (j * 16 + row)) * HW + hw] = acc[t][j][r];
      }
    }
  }
}

static inline void launch_transpose(const float* in, float* out, int Oc, int C,
                                    hipStream_t stream) {
  int total = Oc * C * 9;
  hipLaunchKernelGGL(transpose_w_kernel, dim3((total + 255) / 256), dim3(256), 0, stream,
                     in, out, Oc, C);
}

static inline void launch_wgemm(const float* in, _Float16* out, int O, int C,
                                hipStream_t stream) {
  int total = O * C * 9;
  hipLaunchKernelGGL(conv_w_gemm_kernel, dim3((total + 255) / 256), dim3(256), 0, stream,
                     in, out, O, C);
}

extern "C" void kernel_launch(void* const* d_in, const int* in_sizes, int n_in,
                              void* d_out, int out_size, void* d_ws, size_t ws_size,
                              hipStream_t stream) {
  const float* x1  = (const float*)d_in[0];
  const float* y   = (const float*)d_in[1];
  const float* wo1 = (const float*)d_in[2];
  const float* bo1 = (const float*)d_in[3];
  const float* wd1 = (const float*)d_in[4];
  const float* bd1 = (const float*)d_in[5];
  const float* wo2 = (const float*)d_in[6];
  const float* bo2 = (const float*)d_in[7];
  const float* wd2 = (const float*)d_in[8];
  const float* bd2 = (const float*)d_in[9];
  const float* wo3 = (const float*)d_in[10];
  const float* bo3 = (const float*)d_in[11];
  const float* wd3 = (const float*)d_in[12];
  const float* bd3 = (const float*)d_in[13];
  float* out = (float*)d_out;

  char* p = (char*)d_ws;
  auto alloc = [&](size_t bytes) {
    char* r = p;
    p += (bytes + 255) & ~(size_t)255;
    return r;
  };
  float* wtO1 = (float*)alloc(18 * 64 * 9 * 4);
  float* wtO2 = (float*)alloc(18 * 96 * 9 * 4);
  float* wtO3 = (float*)alloc(18 * 96 * 9 * 4);
  _Float16* W1h = (_Float16*)alloc((size_t)96 * 576 * 2);
  _Float16* W2h = (_Float16*)alloc((size_t)96 * 864 * 2);
  _Float16* W3h = (_Float16*)alloc((size_t)64 * 864 * 2);
  float* offs = (float*)alloc((size_t)B * KOFF * HW * 4);
  float* h1   = (float*)alloc((size_t)NPIX * 96 * 4);
  float* h2   = (float*)alloc((size_t)NPIX * 96 * 4);
  _Float16* samp = (_Float16*)alloc((size_t)NPIX * 864 * 2);

  launch_transpose(wo1, wtO1, 18, 64, stream);
  launch_transpose(wo2, wtO2, 18, 96, stream);
  launch_transpose(wo3, wtO3, 18, 96, stream);
  launch_wgemm(wd1, W1h, 96, 64, stream);
  launch_wgemm(wd2, W2h, 96, 96, stream);
  launch_wgemm(wd3, W3h, 64, 96, stream);

  dim3 blk(256);
  dim3 gconv(NPIX / 256, 3);
  dim3 ggat(NPIX / 256, 9);
  dim3 ggemm(NPIX / 64);
  dim3 wblk(64);

  // stage 1: offsets from y; deform x1 -> h1 (C=64 -> O=96)
  hipLaunchKernelGGL((offset_conv_kernel<64, 6>), gconv, blk, 0, stream, y, wtO1, bo1, offs);
  hipLaunchKernelGGL((gather_kernel<64>), ggat, blk, 0, stream, x1, offs, samp);
  hipLaunchKernelGGL((gemm_kernel<576, 96>), ggemm, wblk, 0, stream, samp, W1h, bd1, h1);

  // stage 2: h1 -> h2 (C=96 -> O=96)
  hipLaunchKernelGGL((offset_conv_kernel<96, 6>), gconv, blk, 0, stream, h1, wtO2, bo2, offs);
  hipLaunchKernelGGL((gather_kernel<96>), ggat, blk, 0, stream, h1, offs, samp);
  hipLaunchKernelGGL((gemm_kernel<864, 96>), ggemm, wblk, 0, stream, samp, W2h, bd2, h2);

  // stage 3: h2 -> out (C=96 -> O=64)
  hipLaunchKernelGGL((offset_conv_kernel<96, 6>), gconv, blk, 0, stream, h2, wtO3, bo3, offs);
  hipLaunchKernelGGL((gather_kernel<96>), ggat, blk, 0, stream, h2, offs, samp);
  hipLaunchKernelGGL((gemm_kernel<864, 64>), ggemm, wblk, 0, stream, samp, W3h, bd3, out);
}

// Round 3
// 374.184 us; speedup vs baseline: 3.3221x; 1.5125x over previous
//
#include <hip/hip_runtime.h>

constexpr int B = 4, H = 96, W = 96, HW = H * W;
constexpr int NPIX = B * HW;   // 36864
constexpr int KOFF = 18;       // 2*K offset channels

typedef _Float16 half8 __attribute__((ext_vector_type(8)));
typedef _Float16 half4 __attribute__((ext_vector_type(4)));
typedef float f32x4 __attribute__((ext_vector_type(4)));

__device__ __forceinline__ int iclamp(int v, int lo, int hi) {
  return v < lo ? lo : (v > hi ? hi : v);
}

// ---------- weight prep ----------
// fp32 (Oc, C, 3, 3) -> (c*9+k, Oc) for offset conv
__global__ void transpose_w_kernel(const float* __restrict__ in, float* __restrict__ out,
                                   int Oc, int C) {
  int i = blockIdx.x * blockDim.x + threadIdx.x;
  int total = Oc * C * 9;
  if (i >= total) return;
  int k = i % 9;
  int c = (i / 9) % C;
  int o = i / (9 * C);
  out[(c * 9 + k) * Oc + o] = in[i];
}

// fp16 GEMM weights: (O, C, 3, 3) -> [o][kk*C + c]
__global__ void conv_w_gemm_kernel(const float* __restrict__ in, _Float16* __restrict__ out,
                                   int O, int C) {
  int i = blockIdx.x * blockDim.x + threadIdx.x;
  int total = O * C * 9;
  if (i >= total) return;
  int kk = i % 9;
  int c = (i / 9) % C;
  int o = i / (9 * C);
  out[(size_t)o * (C * 9) + kk * C + c] = (_Float16)in[i];
}

// ---------- NCHW fp32 -> NHWC fp16 repack (for stage-1 gather source) ----------
template <int C>
__global__ __launch_bounds__(256) void repack_kernel(const float* __restrict__ in,
                                                     _Float16* __restrict__ outh) {
  __shared__ float tile[64 * C];
  int t = threadIdx.x;
  int pix0 = blockIdx.x * 64;        // 64 | HW, so whole block same batch
  int b = pix0 / HW;
  int hw0 = pix0 - b * HW;
  int l = t & 63;
  for (int cc = t >> 6; cc < C; cc += 4)
    tile[cc * 64 + l] = in[((size_t)b * C + cc) * HW + hw0 + l];
  __syncthreads();
  int pl = t >> 2;            // 0..63 pixel
  int cq = t & 3;             // channel quarter
  _Float16* op = outh + (size_t)(pix0 + pl) * C + cq * (C / 4);
#pragma unroll
  for (int c = 0; c < C / 4; c += 4) {
    half4 hv;
#pragma unroll
    for (int u = 0; u < 4; ++u) hv[u] = (_Float16)tile[(cq * (C / 4) + c + u) * 64 + pl];
    *(half4*)(op + c) = hv;
  }
}

// ---------- offset conv (fp32, unchanged) ----------
template <int C, int OCT>
__global__ void offset_conv_kernel(const float* __restrict__ x, const float* __restrict__ wt,
                                   const float* __restrict__ bo, float* __restrict__ out) {
  int pix = blockIdx.x * blockDim.x + threadIdx.x;
  int ocbase = blockIdx.y * OCT;
  int w = pix % W;
  int h = (pix / W) % H;
  int b = pix / HW;
  float acc[OCT];
#pragma unroll
  for (int i = 0; i < OCT; ++i) acc[i] = bo[ocbase + i];
  const float* xb = x + b * C * HW;
  for (int c = 0; c < C; ++c) {
    const float* xc = xb + c * HW;
#pragma unroll
    for (int ky = 0; ky < 3; ++ky) {
      int yy = h + ky - 1;
      bool yv = (yy >= 0) & (yy < H);
#pragma unroll
      for (int kx = 0; kx < 3; ++kx) {
        int xx = w + kx - 1;
        bool v = yv & (xx >= 0) & (xx < W);
        float val = v ? xc[yy * W + xx] : 0.0f;
        const float* wp = wt + (c * 9 + ky * 3 + kx) * KOFF + ocbase;
#pragma unroll
        for (int i = 0; i < OCT; ++i) acc[i] = fmaf(val, wp[i], acc[i]);
      }
    }
  }
  float* ob = out + b * KOFF * HW + h * W + w;
#pragma unroll
  for (int i = 0; i < OCT; ++i) ob[(ocbase + i) * HW] = acc[i];
}

// ---------- fused deformable conv: gather->LDS->MFMA ----------
// xh: [NPIX][C] fp16 NHWC; off: (B,18,H,W) fp32; wt: [o][k*C+c] fp16
// out: (B,O,HW) fp32; outh (if WH): [NPIX][O] fp16 NHWC
template <int C, int O, bool WH>
__global__ __launch_bounds__(256)
void fused_deform_kernel(const _Float16* __restrict__ xh, const float* __restrict__ off,
                         const _Float16* __restrict__ wt, const float* __restrict__ bd,
                         float* __restrict__ out, _Float16* __restrict__ outh) {
  constexpr int CP = C + 8;       // padded LDS stride (2-way bank max on b128 reads)
  constexpr int NO2 = O / 32;     // 16-wide o-tiles per wave (o-half per wave)
  constexpr int CSPAN = C / 8;    // channels per gather thread
  __shared__ _Float16 smp[32 * CP];
  int t = threadIdx.x;
  int lane = t & 63;
  int wave = t >> 6;
  int mhalf = wave >> 1;
  int obase = (wave & 1) * (O / 2);
  int row = lane & 15;
  int kgrp = lane >> 4;
  int pix0 = blockIdx.x * 32;

  // gather identity: thread covers (pixel gpx, channels [gc0, gc0+CSPAN))
  int gpx = t & 31;
  int gc0 = (t >> 5) * CSPAN;
  int px = pix0 + gpx;
  int b = px / HW;
  int hw = px - b * HW;
  int h = hw / W;
  int w = hw - h * W;
  const float* offp = off + (size_t)b * KOFF * HW + hw;
  const _Float16* xb = xh + (size_t)b * HW * C;
  _Float16* sp = smp + gpx * CP + gc0;

  f32x4 acc[NO2];
#pragma unroll
  for (int j = 0; j < NO2; ++j) {
    float bv = bd[obase + j * 16 + row];
    acc[j] = {bv, bv, bv, bv};
  }
  const int arow = mhalf * 16 + row;

  for (int k = 0; k < 9; ++k) {
    __syncthreads();   // previous tap's GEMM reads done
    // ---- gather 32 x C into LDS ----
    {
      float dy = offp[(2 * k) * HW];
      float dx = offp[(2 * k + 1) * HW];
      float py = dy + (float)(k / 3 + h - 1);
      float qx = dx + (float)(k % 3 + w - 1);
      float fy = floorf(py), fx = floorf(qx);
      float wy = py - fy, wx = qx - fx;
      int y0 = (int)fy, x0 = (int)fx;
      int y1 = y0 + 1, x1 = x0 + 1;
      bool vy0 = (y0 >= 0) & (y0 < H);
      bool vy1 = (y1 >= 0) & (y1 < H);
      bool vx0 = (x0 >= 0) & (x0 < W);
      bool vx1 = (x1 >= 0) & (x1 < W);
      int r0 = iclamp(y0, 0, H - 1) * W;
      int r1 = iclamp(y1, 0, H - 1) * W;
      int c0 = iclamp(x0, 0, W - 1);
      int c1 = iclamp(x1, 0, W - 1);
      float w00 = (1.f - wy) * (1.f - wx) * ((vy0 & vx0) ? 1.f : 0.f);
      float w01 = (1.f - wy) * wx * ((vy0 & vx1) ? 1.f : 0.f);
      float w10 = wy * (1.f - wx) * ((vy1 & vx0) ? 1.f : 0.f);
      float w11 = wy * wx * ((vy1 & vx1) ? 1.f : 0.f);
      const _Float16* p00 = xb + (size_t)(r0 + c0) * C + gc0;
      const _Float16* p01 = xb + (size_t)(r0 + c1) * C + gc0;
      const _Float16* p10 = xb + (size_t)(r1 + c0) * C + gc0;
      const _Float16* p11 = xb + (size_t)(r1 + c1) * C + gc0;
#pragma unroll
      for (int q = 0; q < CSPAN / 4; ++q) {
        half4 v00 = *(const half4*)(p00 + q * 4);
        half4 v01 = *(const half4*)(p01 + q * 4);
        half4 v10 = *(const half4*)(p10 + q * 4);
        half4 v11 = *(const half4*)(p11 + q * 4);
        half4 r;
#pragma unroll
        for (int u = 0; u < 4; ++u) {
          float s = (float)v00[u] * w00 + (float)v01[u] * w01 +
                    (float)v10[u] * w10 + (float)v11[u] * w11;
          r[u] = (_Float16)s;
        }
        *(half4*)(sp + q * 4) = r;
      }
    }
    __syncthreads();   // LDS tile ready
    // ---- MFMA over this tap's C channels ----
    const _Float16* wk = wt + (size_t)k * C;
#pragma unroll
    for (int ks = 0; ks < C / 32; ++ks) {
      int kb = ks * 32 + kgrp * 8;
      half8 a = *(const half8*)(smp + arow * CP + kb);
#pragma unroll
      for (int j = 0; j < NO2; ++j) {
        half8 bf = *(const half8*)(wk + (size_t)(obase + j * 16 + row) * (9 * C) + kb);
        acc[j] = __builtin_amdgcn_mfma_f32_16x16x32_f16(a, bf, acc[j], 0, 0, 0);
      }
    }
  }
  // ---- epilogue: NCHW fp32 (+ NHWC fp16) ----
#pragma unroll
  for (int j = 0; j < NO2; ++j) {
    int o = obase + j * 16 + row;
#pragma unroll
    for (int r = 0; r < 4; ++r) {
      int p = pix0 + mhalf * 16 + kgrp * 4 + r;
      int pb = p / HW;
      int phw = p - pb * HW;
      out[((size_t)pb * O + o) * HW + phw] = acc[j][r];
      if (WH) outh[(size_t)p * O + o] = (_Float16)acc[j][r];
    }
  }
}

static inline void launch_transpose(const float* in, float* out, int Oc, int C,
                                    hipStream_t stream) {
  int total = Oc * C * 9;
  hipLaunchKernelGGL(transpose_w_kernel, dim3((total + 255) / 256), dim3(256), 0, stream,
                     in, out, Oc, C);
}

static inline void launch_wgemm(const float* in, _Float16* out, int O, int C,
                                hipStream_t stream) {
  int total = O * C * 9;
  hipLaunchKernelGGL(conv_w_gemm_kernel, dim3((total + 255) / 256), dim3(256), 0, stream,
                     in, out, O, C);
}

extern "C" void kernel_launch(void* const* d_in, const int* in_sizes, int n_in,
                              void* d_out, int out_size, void* d_ws, size_t ws_size,
                              hipStream_t stream) {
  const float* x1  = (const float*)d_in[0];
  const float* y   = (const float*)d_in[1];
  const float* wo1 = (const float*)d_in[2];
  const float* bo1 = (const float*)d_in[3];
  const float* wd1 = (const float*)d_in[4];
  const float* bd1 = (const float*)d_in[5];
  const float* wo2 = (const float*)d_in[6];
  const float* bo2 = (const float*)d_in[7];
  const float* wd2 = (const float*)d_in[8];
  const float* bd2 = (const float*)d_in[9];
  const float* wo3 = (const float*)d_in[10];
  const float* bo3 = (const float*)d_in[11];
  const float* wd3 = (const float*)d_in[12];
  const float* bd3 = (const float*)d_in[13];
  float* out = (float*)d_out;

  char* p = (char*)d_ws;
  auto alloc = [&](size_t bytes) {
    char* r = p;
    p += (bytes + 255) & ~(size_t)255;
    return r;
  };
  float* wtO1 = (float*)alloc(18 * 64 * 9 * 4);
  float* wtO2 = (float*)alloc(18 * 96 * 9 * 4);
  float* wtO3 = (float*)alloc(18 * 96 * 9 * 4);
  _Float16* W1h = (_Float16*)alloc((size_t)96 * 576 * 2);
  _Float16* W2h = (_Float16*)alloc((size_t)96 * 864 * 2);
  _Float16* W3h = (_Float16*)alloc((size_t)64 * 864 * 2);
  float* offs = (float*)alloc((size_t)B * KOFF * HW * 4);
  float* h1   = (float*)alloc((size_t)NPIX * 96 * 4);      // NCHW fp32
  float* h2   = (float*)alloc((size_t)NPIX * 96 * 4);
  _Float16* x1h = (_Float16*)alloc((size_t)NPIX * 64 * 2); // NHWC fp16
  _Float16* h1h = (_Float16*)alloc((size_t)NPIX * 96 * 2);
  _Float16* h2h = (_Float16*)alloc((size_t)NPIX * 96 * 2);

  launch_transpose(wo1, wtO1, 18, 64, stream);
  launch_transpose(wo2, wtO2, 18, 96, stream);
  launch_transpose(wo3, wtO3, 18, 96, stream);
  launch_wgemm(wd1, W1h, 96, 64, stream);
  launch_wgemm(wd2, W2h, 96, 96, stream);
  launch_wgemm(wd3, W3h, 64, 96, stream);
  hipLaunchKernelGGL((repack_kernel<64>), dim3(NPIX / 64), dim3(256), 0, stream, x1, x1h);

  dim3 blk(256);
  dim3 gconv(NPIX / 256, 3);
  dim3 gfuse(NPIX / 32);

  // stage 1: offsets from y; deform x1 -> h1 (C=64 -> O=96)
  hipLaunchKernelGGL((offset_conv_kernel<64, 6>), gconv, blk, 0, stream, y, wtO1, bo1, offs);
  hipLaunchKernelGGL((fused_deform_kernel<64, 96, true>), gfuse, blk, 0, stream,
                     x1h, offs, W1h, bd1, h1, h1h);

  // stage 2: h1 -> h2 (C=96 -> O=96)
  hipLaunchKernelGGL((offset_conv_kernel<96, 6>), gconv, blk, 0, stream, h1, wtO2, bo2, offs);
  hipLaunchKernelGGL((fused_deform_kernel<96, 96, true>), gfuse, blk, 0, stream,
                     h1h, offs, W2h, bd2, h2, h2h);

  // stage 3: h2 -> out (C=96 -> O=64)
  hipLaunchKernelGGL((offset_conv_kernel<96, 6>), gconv, blk, 0, stream, h2, wtO3, bo3, offs);
  hipLaunchKernelGGL((fused_deform_kernel<96, 64, false>), gfuse, blk, 0, stream,
                     h2h, offs, W3h, bd3, out, (_Float16*)nullptr);
}

// Round 4
// 241.843 us; speedup vs baseline: 5.1400x; 1.5472x over previous
//
#include <hip/hip_runtime.h>

constexpr int B = 4, H = 96, W = 96, HW = H * W;
constexpr int NPIX = B * HW;   // 36864
constexpr int KOFF = 18;       // 2*K offset channels

typedef _Float16 half8 __attribute__((ext_vector_type(8)));
typedef _Float16 half4 __attribute__((ext_vector_type(4)));
typedef float f32x4 __attribute__((ext_vector_type(4)));

__device__ __forceinline__ int iclamp(int v, int lo, int hi) {
  return v < lo ? lo : (v > hi ? hi : v);
}

// ---------- weight prep: fp32 (O, C, 3, 3) -> fp16 [o][kk*C + c] ----------
__global__ void conv_w_gemm_kernel(const float* __restrict__ in, _Float16* __restrict__ out,
                                   int O, int C) {
  int i = blockIdx.x * blockDim.x + threadIdx.x;
  int total = O * C * 9;
  if (i >= total) return;
  int kk = i % 9;
  int c = (i / 9) % C;
  int o = i / (9 * C);
  out[(size_t)o * (C * 9) + kk * C + c] = (_Float16)in[i];
}

// ---------- NCHW fp32 -> NHWC fp16 repack ----------
template <int C>
__global__ __launch_bounds__(256) void repack_kernel(const float* __restrict__ in,
                                                     _Float16* __restrict__ outh) {
  __shared__ float tile[64 * C];
  int t = threadIdx.x;
  int pix0 = blockIdx.x * 64;        // 64 | HW, so whole block same batch
  int b = pix0 / HW;
  int hw0 = pix0 - b * HW;
  int l = t & 63;
  for (int cc = t >> 6; cc < C; cc += 4)
    tile[cc * 64 + l] = in[((size_t)b * C + cc) * HW + hw0 + l];
  __syncthreads();
  int pl = t >> 2;            // 0..63 pixel
  int cq = t & 3;             // channel quarter
  _Float16* op = outh + (size_t)(pix0 + pl) * C + cq * (C / 4);
#pragma unroll
  for (int c = 0; c < C / 4; c += 4) {
    half4 hv;
#pragma unroll
    for (int u = 0; u < 4; ++u) hv[u] = (_Float16)tile[(cq * (C / 4) + c + u) * 64 + pl];
    *(half4*)(op + c) = hv;
  }
}

// ---------- MFMA offset conv: 3x3 pad-1 conv, O=18 padded to 32 ----------
// xh: [NPIX][C] fp16 NHWC; wt: [32][9*C] fp16 (rows 18..31 zero); offs: (B,18,HW) fp32
template <int C>
__global__ __launch_bounds__(256)
void offset_mfma_kernel(const _Float16* __restrict__ xh, const _Float16* __restrict__ wt,
                        const float* __restrict__ bo, float* __restrict__ offs) {
  constexpr int CP = C + 8;
  constexpr int CSPAN = C / 8;
  __shared__ _Float16 smp[32 * CP];
  int t = threadIdx.x;
  int lane = t & 63;
  int wave = t >> 6;
  int mhalf = wave >> 1;
  int obase = (wave & 1) * 16;
  int row = lane & 15;
  int kgrp = lane >> 4;
  int pix0 = blockIdx.x * 32;

  int gpx = t & 31;
  int gc0 = (t >> 5) * CSPAN;
  int px = pix0 + gpx;
  int b = px / HW;
  int hw = px - b * HW;
  int h = hw / W;
  int w = hw - h * W;
  const _Float16* xb = xh + (size_t)b * HW * C;
  _Float16* sp = smp + gpx * CP + gc0;

  int o = obase + row;
  f32x4 acc;
  {
    float bv = (o < KOFF) ? bo[o] : 0.f;
    acc = {bv, bv, bv, bv};
  }
  const int arow = mhalf * 16 + row;

  for (int k = 0; k < 9; ++k) {
    __syncthreads();
    {
      int yy = h + (k / 3) - 1;
      int xx = w + (k % 3) - 1;
      bool v = (yy >= 0) & (yy < H) & (xx >= 0) & (xx < W);
      const _Float16* pv = xb + (size_t)(yy * W + xx) * C + gc0;
#pragma unroll
      for (int q = 0; q < CSPAN / 4; ++q) {
        half4 r = {0, 0, 0, 0};
        if (v) r = *(const half4*)(pv + q * 4);
        *(half4*)(sp + q * 4) = r;
      }
    }
    __syncthreads();
    const _Float16* wk = wt + (size_t)k * C;
#pragma unroll
    for (int ks = 0; ks < C / 32; ++ks) {
      int kb = ks * 32 + kgrp * 8;
      half8 a = *(const half8*)(smp + arow * CP + kb);
      half8 bf = *(const half8*)(wk + (size_t)o * (9 * C) + kb);
      acc = __builtin_amdgcn_mfma_f32_16x16x32_f16(a, bf, acc, 0, 0, 0);
    }
  }
  if (o < KOFF) {
#pragma unroll
    for (int r = 0; r < 4; ++r) {
      int p = pix0 + mhalf * 16 + kgrp * 4 + r;
      int pb = p / HW;
      int phw = p - pb * HW;
      offs[((size_t)pb * KOFF + o) * HW + phw] = acc[r];
    }
  }
}

// ---------- fused deformable conv: gather->LDS->MFMA ----------
// xh: [NPIX][C] fp16 NHWC; off: (B,18,H,W) fp32; wt: [o][k*C+c] fp16
// WF32: write (B,O,HW) fp32; WH: write [NPIX][O] fp16 NHWC
template <int C, int O, bool WF32, bool WH>
__global__ __launch_bounds__(256)
void fused_deform_kernel(const _Float16* __restrict__ xh, const float* __restrict__ off,
                         const _Float16* __restrict__ wt, const float* __restrict__ bd,
                         float* __restrict__ out, _Float16* __restrict__ outh) {
  constexpr int CP = C + 8;       // padded LDS stride
  constexpr int NO2 = O / 32;     // 16-wide o-tiles per wave (o-half per wave)
  constexpr int CSPAN = C / 8;    // channels per gather thread
  __shared__ _Float16 smp[32 * CP];
  int t = threadIdx.x;
  int lane = t & 63;
  int wave = t >> 6;
  int mhalf = wave >> 1;
  int obase = (wave & 1) * (O / 2);
  int row = lane & 15;
  int kgrp = lane >> 4;
  int pix0 = blockIdx.x * 32;

  int gpx = t & 31;
  int gc0 = (t >> 5) * CSPAN;
  int px = pix0 + gpx;
  int b = px / HW;
  int hw = px - b * HW;
  int h = hw / W;
  int w = hw - h * W;
  const float* offp = off + (size_t)b * KOFF * HW + hw;
  const _Float16* xb = xh + (size_t)b * HW * C;
  _Float16* sp = smp + gpx * CP + gc0;

  f32x4 acc[NO2];
#pragma unroll
  for (int j = 0; j < NO2; ++j) {
    float bv = bd[obase + j * 16 + row];
    acc[j] = {bv, bv, bv, bv};
  }
  const int arow = mhalf * 16 + row;

  for (int k = 0; k < 9; ++k) {
    __syncthreads();   // previous tap's GEMM reads done
    {
      float dy = offp[(2 * k) * HW];
      float dx = offp[(2 * k + 1) * HW];
      float py = dy + (float)(k / 3 + h - 1);
      float qx = dx + (float)(k % 3 + w - 1);
      float fy = floorf(py), fx = floorf(qx);
      float wy = py - fy, wx = qx - fx;
      int y0 = (int)fy, x0 = (int)fx;
      int y1 = y0 + 1, x1 = x0 + 1;
      bool vy0 = (y0 >= 0) & (y0 < H);
      bool vy1 = (y1 >= 0) & (y1 < H);
      bool vx0 = (x0 >= 0) & (x0 < W);
      bool vx1 = (x1 >= 0) & (x1 < W);
      int r0 = iclamp(y0, 0, H - 1) * W;
      int r1 = iclamp(y1, 0, H - 1) * W;
      int c0 = iclamp(x0, 0, W - 1);
      int c1 = iclamp(x1, 0, W - 1);
      float w00 = (1.f - wy) * (1.f - wx) * ((vy0 & vx0) ? 1.f : 0.f);
      float w01 = (1.f - wy) * wx * ((vy0 & vx1) ? 1.f : 0.f);
      float w10 = wy * (1.f - wx) * ((vy1 & vx0) ? 1.f : 0.f);
      float w11 = wy * wx * ((vy1 & vx1) ? 1.f : 0.f);
      const _Float16* p00 = xb + (size_t)(r0 + c0) * C + gc0;
      const _Float16* p01 = xb + (size_t)(r0 + c1) * C + gc0;
      const _Float16* p10 = xb + (size_t)(r1 + c0) * C + gc0;
      const _Float16* p11 = xb + (size_t)(r1 + c1) * C + gc0;
#pragma unroll
      for (int q = 0; q < CSPAN / 4; ++q) {
        half4 v00 = *(const half4*)(p00 + q * 4);
        half4 v01 = *(const half4*)(p01 + q * 4);
        half4 v10 = *(const half4*)(p10 + q * 4);
        half4 v11 = *(const half4*)(p11 + q * 4);
        half4 r;
#pragma unroll
        for (int u = 0; u < 4; ++u) {
          float s = (float)v00[u] * w00 + (float)v01[u] * w01 +
                    (float)v10[u] * w10 + (float)v11[u] * w11;
          r[u] = (_Float16)s;
        }
        *(half4*)(sp + q * 4) = r;
      }
    }
    __syncthreads();   // LDS tile ready
    const _Float16* wk = wt + (size_t)k * C;
#pragma unroll
    for (int ks = 0; ks < C / 32; ++ks) {
      int kb = ks * 32 + kgrp * 8;
      half8 a = *(const half8*)(smp + arow * CP + kb);
#pragma unroll
      for (int j = 0; j < NO2; ++j) {
        half8 bf = *(const half8*)(wk + (size_t)(obase + j * 16 + row) * (9 * C) + kb);
        acc[j] = __builtin_amdgcn_mfma_f32_16x16x32_f16(a, bf, acc[j], 0, 0, 0);
      }
    }
  }
  // ---- epilogue ----
#pragma unroll
  for (int j = 0; j < NO2; ++j) {
    int o = obase + j * 16 + row;
#pragma unroll
    for (int r = 0; r < 4; ++r) {
      int p = pix0 + mhalf * 16 + kgrp * 4 + r;
      if (WF32) {
        int pb = p / HW;
        int phw = p - pb * HW;
        out[((size_t)pb * O + o) * HW + phw] = acc[j][r];
      }
      if (WH) outh[(size_t)p * O + o] = (_Float16)acc[j][r];
    }
  }
}

static inline void launch_wgemm(const float* in, _Float16* out, int O, int C,
                                hipStream_t stream) {
  int total = O * C * 9;
  hipLaunchKernelGGL(conv_w_gemm_kernel, dim3((total + 255) / 256), dim3(256), 0, stream,
                     in, out, O, C);
}

extern "C" void kernel_launch(void* const* d_in, const int* in_sizes, int n_in,
                              void* d_out, int out_size, void* d_ws, size_t ws_size,
                              hipStream_t stream) {
  const float* x1  = (const float*)d_in[0];
  const float* y   = (const float*)d_in[1];
  const float* wo1 = (const float*)d_in[2];
  const float* bo1 = (const float*)d_in[3];
  const float* wd1 = (const float*)d_in[4];
  const float* bd1 = (const float*)d_in[5];
  const float* wo2 = (const float*)d_in[6];
  const float* bo2 = (const float*)d_in[7];
  const float* wd2 = (const float*)d_in[8];
  const float* bd2 = (const float*)d_in[9];
  const float* wo3 = (const float*)d_in[10];
  const float* bo3 = (const float*)d_in[11];
  const float* wd3 = (const float*)d_in[12];
  const float* bd3 = (const float*)d_in[13];
  float* out = (float*)d_out;

  char* p = (char*)d_ws;
  auto alloc = [&](size_t bytes) {
    char* r = p;
    p += (bytes + 255) & ~(size_t)255;
    return r;
  };
  // padded offset-conv weights (32 rows, rows 18..31 zero) — contiguous for one memset
  _Float16* WoP1 = (_Float16*)alloc((size_t)32 * 576 * 2);
  _Float16* WoP2 = (_Float16*)alloc((size_t)32 * 864 * 2);
  _Float16* WoP3 = (_Float16*)alloc((size_t)32 * 864 * 2);
  _Float16* W1h  = (_Float16*)alloc((size_t)96 * 576 * 2);
  _Float16* W2h  = (_Float16*)alloc((size_t)96 * 864 * 2);
  _Float16* W3h  = (_Float16*)alloc((size_t)64 * 864 * 2);
  float* offs = (float*)alloc((size_t)B * KOFF * HW * 4);
  _Float16* x1h = (_Float16*)alloc((size_t)NPIX * 64 * 2); // NHWC fp16
  _Float16* yh  = (_Float16*)alloc((size_t)NPIX * 64 * 2);
  _Float16* h1h = (_Float16*)alloc((size_t)NPIX * 96 * 2);
  _Float16* h2h = (_Float16*)alloc((size_t)NPIX * 96 * 2);

  // zero the padded offset-weight region (covers WoP1..WoP3 contiguously)
  hipMemsetAsync(WoP1, 0, (char*)W1h - (char*)WoP1, stream);

  launch_wgemm(wo1, WoP1, 18, 64, stream);   // rows 0..17; 18..31 stay zero
  launch_wgemm(wo2, WoP2, 18, 96, stream);
  launch_wgemm(wo3, WoP3, 18, 96, stream);
  launch_wgemm(wd1, W1h, 96, 64, stream);
  launch_wgemm(wd2, W2h, 96, 96, stream);
  launch_wgemm(wd3, W3h, 64, 96, stream);
  hipLaunchKernelGGL((repack_kernel<64>), dim3(NPIX / 64), dim3(256), 0, stream, x1, x1h);
  hipLaunchKernelGGL((repack_kernel<64>), dim3(NPIX / 64), dim3(256), 0, stream, y, yh);

  dim3 blk(256);
  dim3 gfuse(NPIX / 32);

  // stage 1: offsets from y; deform x1 -> h1h (C=64 -> O=96)
  hipLaunchKernelGGL((offset_mfma_kernel<64>), gfuse, blk, 0, stream, yh, WoP1, bo1, offs);
  hipLaunchKernelGGL((fused_deform_kernel<64, 96, false, true>), gfuse, blk, 0, stream,
                     x1h, offs, W1h, bd1, (float*)nullptr, h1h);

  // stage 2: h1 -> h2h (C=96 -> O=96)
  hipLaunchKernelGGL((offset_mfma_kernel<96>), gfuse, blk, 0, stream, h1h, WoP2, bo2, offs);
  hipLaunchKernelGGL((fused_deform_kernel<96, 96, false, true>), gfuse, blk, 0, stream,
                     h1h, offs, W2h, bd2, (float*)nullptr, h2h);

  // stage 3: h2 -> out (C=96 -> O=64)
  hipLaunchKernelGGL((offset_mfma_kernel<96>), gfuse, blk, 0, stream, h2h, WoP3, bo3, offs);
  hipLaunchKernelGGL((fused_deform_kernel<96, 64, true, false>), gfuse, blk, 0, stream,
                     h2h, offs, W3h, bd3, out, (_Float16*)nullptr);
}

// Round 5
// 177.917 us; speedup vs baseline: 6.9867x; 1.3593x over previous
//
#include <hip/hip_runtime.h>

constexpr int B = 4, H = 96, W = 96, HW = H * W;
constexpr int NPIX = B * HW;   // 36864
constexpr int KOFF = 18;       // 2*K offset channels

typedef _Float16 half8 __attribute__((ext_vector_type(8)));
typedef _Float16 half4 __attribute__((ext_vector_type(4)));
typedef float f32x4 __attribute__((ext_vector_type(4)));

__device__ __forceinline__ int iclamp(int v, int lo, int hi) {
  return v < lo ? lo : (v > hi ? hi : v);
}

struct Corners {
  int i00, i01, i10, i11;
  float w00, w01, w10, w11;
};

__device__ __forceinline__ Corners mk_corners(float py, float qx) {
  float fy = floorf(py), fx = floorf(qx);
  float wy = py - fy, wx = qx - fx;
  int y0 = (int)fy, x0 = (int)fx;
  int y1 = y0 + 1, x1 = x0 + 1;
  bool vy0 = (y0 >= 0) & (y0 < H);
  bool vy1 = (y1 >= 0) & (y1 < H);
  bool vx0 = (x0 >= 0) & (x0 < W);
  bool vx1 = (x1 >= 0) & (x1 < W);
  int r0 = iclamp(y0, 0, H - 1) * W;
  int r1 = iclamp(y1, 0, H - 1) * W;
  int c0 = iclamp(x0, 0, W - 1);
  int c1 = iclamp(x1, 0, W - 1);
  Corners cc;
  cc.i00 = r0 + c0; cc.i01 = r0 + c1; cc.i10 = r1 + c0; cc.i11 = r1 + c1;
  float a = 1.f - wy, bb = 1.f - wx;
  cc.w00 = a * bb * ((vy0 & vx0) ? 1.f : 0.f);
  cc.w01 = a * wx * ((vy0 & vx1) ? 1.f : 0.f);
  cc.w10 = wy * bb * ((vy1 & vx0) ? 1.f : 0.f);
  cc.w11 = wy * wx * ((vy1 & vx1) ? 1.f : 0.f);
  return cc;
}

__device__ __forceinline__ half8 interp8(half8 v00, half8 v01, half8 v10, half8 v11,
                                         const Corners& cc) {
  half8 r;
#pragma unroll
  for (int u = 0; u < 8; ++u) {
    float s = (float)v00[u] * cc.w00 + (float)v01[u] * cc.w01 +
              (float)v10[u] * cc.w10 + (float)v11[u] * cc.w11;
    r[u] = (_Float16)s;
  }
  return r;
}

// ---------- weight prep: (Osrc, C, 3, 3) fp32 -> fragment order fp16 ----------
// wf[((k*KS + ks)*NJ + j)*64 + lane][8]: o = j*16+(lane&15), c = ks*32+(lane>>4)*8+u
__global__ void wfrag_kernel(const float* __restrict__ wsrc, _Float16* __restrict__ wf,
                             int C, int Osrc, int OPAD) {
  int KS = C / 32;
  int NJ = OPAD / 16;
  int fid = blockIdx.x;            // k*KS*NJ + ks*NJ + j
  int lane = threadIdx.x;
  int j = fid % NJ;
  int ks = (fid / NJ) % KS;
  int k = fid / (NJ * KS);
  int o = j * 16 + (lane & 15);
  int c0 = ks * 32 + (lane >> 4) * 8;
  half8 v;
#pragma unroll
  for (int u = 0; u < 8; ++u)
    v[u] = (o < Osrc) ? (_Float16)wsrc[((size_t)o * C + c0 + u) * 9 + k] : (_Float16)0.f;
  *(half8*)(wf + ((size_t)fid * 64 + lane) * 8) = v;
}

// ---------- NCHW fp32 -> NHWC fp16 repack ----------
template <int C>
__global__ __launch_bounds__(256) void repack_kernel(const float* __restrict__ in,
                                                     _Float16* __restrict__ outh) {
  __shared__ float tile[64 * C];
  int t = threadIdx.x;
  int pix0 = blockIdx.x * 64;
  int b = pix0 / HW;
  int hw0 = pix0 - b * HW;
  int l = t & 63;
  for (int cc = t >> 6; cc < C; cc += 4)
    tile[cc * 64 + l] = in[((size_t)b * C + cc) * HW + hw0 + l];
  __syncthreads();
  int pl = t >> 2;
  int cq = t & 3;
  _Float16* op = outh + (size_t)(pix0 + pl) * C + cq * (C / 4);
#pragma unroll
  for (int c = 0; c < C / 4; c += 4) {
    half4 hv;
#pragma unroll
    for (int u = 0; u < 4; ++u) hv[u] = (_Float16)tile[(cq * (C / 4) + c + u) * 64 + pl];
    *(half4*)(op + c) = hv;
  }
}

// ---------- offset conv, register GEMM, no barriers: O=18 padded to 32 ----------
// xh: [NPIX][C] fp16; wf: fragment order; offs out: [px][18] fp32
template <int C>
__global__ __launch_bounds__(64, 1)
void offset_reg_kernel(const _Float16* __restrict__ xh, const _Float16* __restrict__ wf,
                       const float* __restrict__ bo, float* __restrict__ offs) {
  constexpr int KS = C / 32;
  constexpr int NJ = 2;   // O padded to 32
  const int lane = threadIdx.x;
  const int row = lane & 15;
  const int kgrp = lane >> 4;
  const int ch = kgrp * 8;
  const int px0 = blockIdx.x * 32;
  const int b = px0 / HW;          // uniform over wave
  const int hw0 = px0 - b * HW;
  const int hwm0 = hw0 + row, hwm1 = hw0 + 16 + row;
  const int h0 = hwm0 / W, w0 = hwm0 - h0 * W;
  const int h1 = hwm1 / W, w1 = hwm1 - h1 * W;
  const _Float16* xb = xh + (size_t)b * HW * C;

  f32x4 acc0[NJ], acc1[NJ];
#pragma unroll
  for (int j = 0; j < NJ; ++j) {
    int o = j * 16 + row;
    float bv = (o < KOFF) ? bo[o] : 0.f;
    acc0[j] = {bv, bv, bv, bv};
    acc1[j] = {bv, bv, bv, bv};
  }

#pragma unroll 1
  for (int k = 0; k < 9; ++k) {
    int ky = k / 3 - 1, kx = k % 3 - 1;
    half8 a0[KS], a1[KS];
    {
      int yy = h0 + ky, xx = w0 + kx;
      bool v = (yy >= 0) & (yy < H) & (xx >= 0) & (xx < W);
      const _Float16* pv = xb + (size_t)(yy * W + xx) * C + ch;
#pragma unroll
      for (int ks = 0; ks < KS; ++ks) {
        half8 r = {0, 0, 0, 0, 0, 0, 0, 0};
        if (v) r = *(const half8*)(pv + ks * 32);
        a0[ks] = r;
      }
    }
    {
      int yy = h1 + ky, xx = w1 + kx;
      bool v = (yy >= 0) & (yy < H) & (xx >= 0) & (xx < W);
      const _Float16* pv = xb + (size_t)(yy * W + xx) * C + ch;
#pragma unroll
      for (int ks = 0; ks < KS; ++ks) {
        half8 r = {0, 0, 0, 0, 0, 0, 0, 0};
        if (v) r = *(const half8*)(pv + ks * 32);
        a1[ks] = r;
      }
    }
    const _Float16* wk = wf + (size_t)k * (KS * NJ * 512);
#pragma unroll
    for (int ks = 0; ks < KS; ++ks) {
#pragma unroll
      for (int j = 0; j < NJ; ++j) {
        half8 bfr = *(const half8*)(wk + ((size_t)(ks * NJ + j) * 64 + lane) * 8);
        acc0[j] = __builtin_amdgcn_mfma_f32_16x16x32_f16(a0[ks], bfr, acc0[j], 0, 0, 0);
        acc1[j] = __builtin_amdgcn_mfma_f32_16x16x32_f16(a1[ks], bfr, acc1[j], 0, 0, 0);
      }
    }
  }
#pragma unroll
  for (int j = 0; j < NJ; ++j) {
    int o = j * 16 + row;
    if (o < KOFF) {
#pragma unroll
      for (int r = 0; r < 4; ++r) {
        offs[(size_t)(px0 + kgrp * 4 + r) * KOFF + o] = acc0[j][r];
        offs[(size_t)(px0 + 16 + kgrp * 4 + r) * KOFF + o] = acc1[j][r];
      }
    }
  }
}

// ---------- deformable conv, register GEMM, no barriers ----------
// xh: [NPIX][C] fp16; offs: [px][9][2] fp32; wf: fragment order
template <int C, int O, bool WF32, bool WH>
__global__ __launch_bounds__(64, 1)
void deform_reg_kernel(const _Float16* __restrict__ xh, const float* __restrict__ offs,
                       const _Float16* __restrict__ wf, const float* __restrict__ bd,
                       float* __restrict__ out, _Float16* __restrict__ outh) {
  constexpr int KS = C / 32;
  constexpr int NJ = O / 16;
  const int lane = threadIdx.x;
  const int row = lane & 15;
  const int kgrp = lane >> 4;
  const int ch = kgrp * 8;
  const int px0 = blockIdx.x * 32;
  const int b = px0 / HW;          // uniform over wave
  const int hw0 = px0 - b * HW;
  const int hwm0 = hw0 + row, hwm1 = hw0 + 16 + row;
  const int h0 = hwm0 / W, w0 = hwm0 - h0 * W;
  const int h1 = hwm1 / W, w1 = hwm1 - h1 * W;
  const _Float16* xb = xh + (size_t)b * HW * C;
  const float2* op = (const float2*)offs;
  const size_t ob0 = (size_t)(px0 + row) * 9;
  const size_t ob1 = (size_t)(px0 + 16 + row) * 9;

  float2 oc0 = op[ob0];
  float2 oc1 = op[ob1];

  f32x4 acc0[NJ], acc1[NJ];
#pragma unroll
  for (int j = 0; j < NJ; ++j) {
    float bv = bd[j * 16 + row];
    acc0[j] = {bv, bv, bv, bv};
    acc1[j] = {bv, bv, bv, bv};
  }

#pragma unroll 1
  for (int k = 0; k < 9; ++k) {
    float2 on0 = oc0, on1 = oc1;
    if (k < 8) { on0 = op[ob0 + k + 1]; on1 = op[ob1 + k + 1]; }  // prefetch next tap
    float kyf = (float)(k / 3 - 1), kxf = (float)(k % 3 - 1);
    half8 a0[KS], a1[KS];
    {
      Corners cc = mk_corners(oc0.x + (float)h0 + kyf, oc0.y + (float)w0 + kxf);
      const _Float16* p00 = xb + (size_t)cc.i00 * C + ch;
      const _Float16* p01 = xb + (size_t)cc.i01 * C + ch;
      const _Float16* p10 = xb + (size_t)cc.i10 * C + ch;
      const _Float16* p11 = xb + (size_t)cc.i11 * C + ch;
#pragma unroll
      for (int ks = 0; ks < KS; ++ks) {
        half8 v00 = *(const half8*)(p00 + ks * 32);
        half8 v01 = *(const half8*)(p01 + ks * 32);
        half8 v10 = *(const half8*)(p10 + ks * 32);
        half8 v11 = *(const half8*)(p11 + ks * 32);
        a0[ks] = interp8(v00, v01, v10, v11, cc);
      }
    }
    {
      Corners cc = mk_corners(oc1.x + (float)h1 + kyf, oc1.y + (float)w1 + kxf);
      const _Float16* p00 = xb + (size_t)cc.i00 * C + ch;
      const _Float16* p01 = xb + (size_t)cc.i01 * C + ch;
      const _Float16* p10 = xb + (size_t)cc.i10 * C + ch;
      const _Float16* p11 = xb + (size_t)cc.i11 * C + ch;
#pragma unroll
      for (int ks = 0; ks < KS; ++ks) {
        half8 v00 = *(const half8*)(p00 + ks * 32);
        half8 v01 = *(const half8*)(p01 + ks * 32);
        half8 v10 = *(const half8*)(p10 + ks * 32);
        half8 v11 = *(const half8*)(p11 + ks * 32);
        a1[ks] = interp8(v00, v01, v10, v11, cc);
      }
    }
    const _Float16* wk = wf + (size_t)k * (KS * NJ * 512);
#pragma unroll
    for (int ks = 0; ks < KS; ++ks) {
#pragma unroll
      for (int j = 0; j < NJ; ++j) {
        half8 bfr = *(const half8*)(wk + ((size_t)(ks * NJ + j) * 64 + lane) * 8);
        acc0[j] = __builtin_amdgcn_mfma_f32_16x16x32_f16(a0[ks], bfr, acc0[j], 0, 0, 0);
        acc1[j] = __builtin_amdgcn_mfma_f32_16x16x32_f16(a1[ks], bfr, acc1[j], 0, 0, 0);
      }
    }
    oc0 = on0; oc1 = on1;
  }
  // epilogue: D col(lane&15)=o, row((lane>>4)*4+r)=pixel-in-tile
#pragma unroll
  for (int j = 0; j < NJ; ++j) {
    int o = j * 16 + row;
#pragma unroll
    for (int r = 0; r < 4; ++r) {
      int p0 = px0 + kgrp * 4 + r;
      int p1 = p0 + 16;
      if (WF32) {
        out[((size_t)b * O + o) * HW + (p0 - b * HW)] = acc0[j][r];
        out[((size_t)b * O + o) * HW + (p1 - b * HW)] = acc1[j][r];
      }
      if (WH) {
        outh[(size_t)p0 * O + o] = (_Float16)acc0[j][r];
        outh[(size_t)p1 * O + o] = (_Float16)acc1[j][r];
      }
    }
  }
}

static inline void launch_wfrag(const float* src, _Float16* dst, int C, int Osrc, int OPAD,
                                hipStream_t stream) {
  int frags = 9 * (C / 32) * (OPAD / 16);
  hipLaunchKernelGGL(wfrag_kernel, dim3(frags), dim3(64), 0, stream, src, dst, C, Osrc, OPAD);
}

extern "C" void kernel_launch(void* const* d_in, const int* in_sizes, int n_in,
                              void* d_out, int out_size, void* d_ws, size_t ws_size,
                              hipStream_t stream) {
  const float* x1  = (const float*)d_in[0];
  const float* y   = (const float*)d_in[1];
  const float* wo1 = (const float*)d_in[2];
  const float* bo1 = (const float*)d_in[3];
  const float* wd1 = (const float*)d_in[4];
  const float* bd1 = (const float*)d_in[5];
  const float* wo2 = (const float*)d_in[6];
  const float* bo2 = (const float*)d_in[7];
  const float* wd2 = (const float*)d_in[8];
  const float* bd2 = (const float*)d_in[9];
  const float* wo3 = (const float*)d_in[10];
  const float* bo3 = (const float*)d_in[11];
  const float* wd3 = (const float*)d_in[12];
  const float* bd3 = (const float*)d_in[13];
  float* out = (float*)d_out;

  char* p = (char*)d_ws;
  auto alloc = [&](size_t bytes) {
    char* r = p;
    p += (bytes + 255) & ~(size_t)255;
    return r;
  };
  _Float16* Wo1f = (_Float16*)alloc((size_t)9 * 2 * 2 * 512 * 2);
  _Float16* Wo2f = (_Float16*)alloc((size_t)9 * 3 * 2 * 512 * 2);
  _Float16* Wo3f = (_Float16*)alloc((size_t)9 * 3 * 2 * 512 * 2);
  _Float16* W1f  = (_Float16*)alloc((size_t)9 * 2 * 6 * 512 * 2);
  _Float16* W2f  = (_Float16*)alloc((size_t)9 * 3 * 6 * 512 * 2);
  _Float16* W3f  = (_Float16*)alloc((size_t)9 * 3 * 4 * 512 * 2);
  float* offs = (float*)alloc((size_t)NPIX * KOFF * 4);   // [px][9][2]
  _Float16* x1h = (_Float16*)alloc((size_t)NPIX * 64 * 2);
  _Float16* yh  = (_Float16*)alloc((size_t)NPIX * 64 * 2);
  _Float16* h1h = (_Float16*)alloc((size_t)NPIX * 96 * 2);
  _Float16* h2h = (_Float16*)alloc((size_t)NPIX * 96 * 2);

  launch_wfrag(wo1, Wo1f, 64, 18, 32, stream);
  launch_wfrag(wo2, Wo2f, 96, 18, 32, stream);
  launch_wfrag(wo3, Wo3f, 96, 18, 32, stream);
  launch_wfrag(wd1, W1f, 64, 96, 96, stream);
  launch_wfrag(wd2, W2f, 96, 96, 96, stream);
  launch_wfrag(wd3, W3f, 96, 64, 64, stream);
  hipLaunchKernelGGL((repack_kernel<64>), dim3(NPIX / 64), dim3(256), 0, stream, x1, x1h);
  hipLaunchKernelGGL((repack_kernel<64>), dim3(NPIX / 64), dim3(256), 0, stream, y, yh);

  dim3 gw(NPIX / 32);
  dim3 wb(64);

  // stage 1: offsets from y; deform x1 -> h1h (C=64 -> O=96)
  hipLaunchKernelGGL((offset_reg_kernel<64>), gw, wb, 0, stream, yh, Wo1f, bo1, offs);
  hipLaunchKernelGGL((deform_reg_kernel<64, 96, false, true>), gw, wb, 0, stream,
                     x1h, offs, W1f, bd1, (float*)nullptr, h1h);

  // stage 2: h1 -> h2h (C=96 -> O=96)
  hipLaunchKernelGGL((offset_reg_kernel<96>), gw, wb, 0, stream, h1h, Wo2f, bo2, offs);
  hipLaunchKernelGGL((deform_reg_kernel<96, 96, false, true>), gw, wb, 0, stream,
                     h1h, offs, W2f, bd2, (float*)nullptr, h2h);

  // stage 3: h2 -> out (C=96 -> O=64)
  hipLaunchKernelGGL((offset_reg_kernel<96>), gw, wb, 0, stream, h2h, Wo3f, bo3, offs);
  hipLaunchKernelGGL((deform_reg_kernel<96, 64, true, false>), gw, wb, 0, stream,
                     h2h, offs, W3f, bd3, out, (_Float16*)nullptr);
}

// Round 6
// 152.594 us; speedup vs baseline: 8.1462x; 1.1660x over previous
//
#include <hip/hip_runtime.h>

constexpr int B = 4, H = 96, W = 96, HW = H * W;
constexpr int NPIX = B * HW;   // 36864
constexpr int KOFF = 18;       // 2*K offset channels

typedef _Float16 half8 __attribute__((ext_vector_type(8)));
typedef _Float16 half4 __attribute__((ext_vector_type(4)));
typedef float f32x4 __attribute__((ext_vector_type(4)));

__device__ __forceinline__ int iclamp(int v, int lo, int hi) {
  return v < lo ? lo : (v > hi ? hi : v);
}

struct Corners {
  int i00, i01, i10, i11;
  float w00, w01, w10, w11;
};

__device__ __forceinline__ Corners mk_corners(float py, float qx) {
  float fy = floorf(py), fx = floorf(qx);
  float wy = py - fy, wx = qx - fx;
  int y0 = (int)fy, x0 = (int)fx;
  int y1 = y0 + 1, x1 = x0 + 1;
  bool vy0 = (y0 >= 0) & (y0 < H);
  bool vy1 = (y1 >= 0) & (y1 < H);
  bool vx0 = (x0 >= 0) & (x0 < W);
  bool vx1 = (x1 >= 0) & (x1 < W);
  int r0 = iclamp(y0, 0, H - 1) * W;
  int r1 = iclamp(y1, 0, H - 1) * W;
  int c0 = iclamp(x0, 0, W - 1);
  int c1 = iclamp(x1, 0, W - 1);
  Corners cc;
  cc.i00 = r0 + c0; cc.i01 = r0 + c1; cc.i10 = r1 + c0; cc.i11 = r1 + c1;
  float a = 1.f - wy, bb = 1.f - wx;
  cc.w00 = a * bb * ((vy0 & vx0) ? 1.f : 0.f);
  cc.w01 = a * wx * ((vy0 & vx1) ? 1.f : 0.f);
  cc.w10 = wy * bb * ((vy1 & vx0) ? 1.f : 0.f);
  cc.w11 = wy * wx * ((vy1 & vx1) ? 1.f : 0.f);
  return cc;
}

// ---------- fragment helpers (all fully inlined, static indexing) ----------
template <int KS>
__device__ __forceinline__ void load_corners(const _Float16* xb, int ch, const Corners& cc,
                                             half8 r[KS][4]) {
  const _Float16* p00 = xb + (size_t)cc.i00 * (KS * 32) + ch;
  const _Float16* p01 = xb + (size_t)cc.i01 * (KS * 32) + ch;
  const _Float16* p10 = xb + (size_t)cc.i10 * (KS * 32) + ch;
  const _Float16* p11 = xb + (size_t)cc.i11 * (KS * 32) + ch;
#pragma unroll
  for (int ks = 0; ks < KS; ++ks) {
    r[ks][0] = *(const half8*)(p00 + ks * 32);
    r[ks][1] = *(const half8*)(p01 + ks * 32);
    r[ks][2] = *(const half8*)(p10 + ks * 32);
    r[ks][3] = *(const half8*)(p11 + ks * 32);
  }
}

template <int KS>
__device__ __forceinline__ void interp_corners(const Corners& cc, half8 r[KS][4],
                                               half8 a[KS]) {
  _Float16 q00 = (_Float16)cc.w00, q01 = (_Float16)cc.w01;
  _Float16 q10 = (_Float16)cc.w10, q11 = (_Float16)cc.w11;
#pragma unroll
  for (int ks = 0; ks < KS; ++ks)
    a[ks] = r[ks][0] * q00 + r[ks][1] * q01 + r[ks][2] * q10 + r[ks][3] * q11;
}

template <int KS>
__device__ __forceinline__ void load_shift(const _Float16* xb, int ch, int h, int w,
                                           int ky, int kx, half8 a[KS]) {
  int yy = h + ky, xx = w + kx;
  bool v = (yy >= 0) & (yy < H) & (xx >= 0) & (xx < W);
  const _Float16* pv = xb + (size_t)(yy * W + xx) * (KS * 32) + ch;
#pragma unroll
  for (int ks = 0; ks < KS; ++ks) {
    half8 r = {0, 0, 0, 0, 0, 0, 0, 0};
    if (v) r = *(const half8*)(pv + ks * 32);
    a[ks] = r;
  }
}

template <int KS, int NJ>
__device__ __forceinline__ void mfma_tap(const _Float16* wk, int lane,
                                         half8 a0[KS], half8 a1[KS],
                                         f32x4 acc0[NJ], f32x4 acc1[NJ]) {
#pragma unroll
  for (int ks = 0; ks < KS; ++ks)
#pragma unroll
    for (int j = 0; j < NJ; ++j) {
      half8 b = *(const half8*)(wk + ((size_t)(ks * NJ + j) * 64 + lane) * 8);
      acc0[j] = __builtin_amdgcn_mfma_f32_16x16x32_f16(a0[ks], b, acc0[j], 0, 0, 0);
      acc1[j] = __builtin_amdgcn_mfma_f32_16x16x32_f16(a1[ks], b, acc1[j], 0, 0, 0);
    }
}

// ---------- weight prep: (Osrc, C, 3, 3) fp32 -> fragment order fp16 ----------
__global__ void wfrag_kernel(const float* __restrict__ wsrc, _Float16* __restrict__ wf,
                             int C, int Osrc, int OPAD) {
  int KS = C / 32;
  int NJ = OPAD / 16;
  int fid = blockIdx.x;            // k*KS*NJ + ks*NJ + j
  int lane = threadIdx.x;
  int j = fid % NJ;
  int ks = (fid / NJ) % KS;
  int k = fid / (NJ * KS);
  int o = j * 16 + (lane & 15);
  int c0 = ks * 32 + (lane >> 4) * 8;
  half8 v;
#pragma unroll
  for (int u = 0; u < 8; ++u)
    v[u] = (o < Osrc) ? (_Float16)wsrc[((size_t)o * C + c0 + u) * 9 + k] : (_Float16)0.f;
  *(half8*)(wf + ((size_t)fid * 64 + lane) * 8) = v;
}

// ---------- NCHW fp32 -> NHWC fp16 repack ----------
template <int C>
__global__ __launch_bounds__(256) void repack_kernel(const float* __restrict__ in,
                                                     _Float16* __restrict__ outh) {
  __shared__ float tile[64 * C];
  int t = threadIdx.x;
  int pix0 = blockIdx.x * 64;
  int b = pix0 / HW;
  int hw0 = pix0 - b * HW;
  int l = t & 63;
  for (int cc = t >> 6; cc < C; cc += 4)
    tile[cc * 64 + l] = in[((size_t)b * C + cc) * HW + hw0 + l];
  __syncthreads();
  int pl = t >> 2;
  int cq = t & 3;
  _Float16* op = outh + (size_t)(pix0 + pl) * C + cq * (C / 4);
#pragma unroll
  for (int c = 0; c < C / 4; c += 4) {
    half4 hv;
#pragma unroll
    for (int u = 0; u < 4; ++u) hv[u] = (_Float16)tile[(cq * (C / 4) + c + u) * 64 + pl];
    *(half4*)(op + c) = hv;
  }
}

// ---------- offset conv, register GEMM, pipelined, no barriers ----------
template <int C>
__global__ __launch_bounds__(64, 1)
void offset_reg_kernel(const _Float16* __restrict__ xh, const _Float16* __restrict__ wf,
                       const float* __restrict__ bo, float* __restrict__ offs) {
  constexpr int KS = C / 32;
  constexpr int NJ = 2;   // O padded to 32
  const int lane = threadIdx.x;
  const int row = lane & 15;
  const int kgrp = lane >> 4;
  const int ch = kgrp * 8;
  const int px0 = blockIdx.x * 32;
  const int b = px0 / HW;
  const int hw0 = px0 - b * HW;
  const int hwm0 = hw0 + row, hwm1 = hw0 + 16 + row;
  const int h0 = hwm0 / W, w0 = hwm0 - h0 * W;
  const int h1 = hwm1 / W, w1 = hwm1 - h1 * W;
  const _Float16* xb = xh + (size_t)b * HW * C;

  f32x4 acc0[NJ], acc1[NJ];
#pragma unroll
  for (int j = 0; j < NJ; ++j) {
    int o = j * 16 + row;
    float bv = (o < KOFF) ? bo[o] : 0.f;
    acc0[j] = {bv, bv, bv, bv};
    acc1[j] = {bv, bv, bv, bv};
  }

  half8 a0[KS], a1[KS];
  load_shift<KS>(xb, ch, h0, w0, -1, -1, a0);
  load_shift<KS>(xb, ch, h1, w1, -1, -1, a1);
#pragma unroll
  for (int k = 0; k < 9; ++k) {
    const _Float16* wk = wf + (size_t)k * (KS * NJ * 512);
    if (k < 8) {
      int kn = k + 1;
      half8 n0[KS], n1[KS];
      load_shift<KS>(xb, ch, h0, w0, kn / 3 - 1, kn % 3 - 1, n0);
      load_shift<KS>(xb, ch, h1, w1, kn / 3 - 1, kn % 3 - 1, n1);
      mfma_tap<KS, NJ>(wk, lane, a0, a1, acc0, acc1);
#pragma unroll
      for (int ks = 0; ks < KS; ++ks) { a0[ks] = n0[ks]; a1[ks] = n1[ks]; }
    } else {
      mfma_tap<KS, NJ>(wk, lane, a0, a1, acc0, acc1);
    }
  }
#pragma unroll
  for (int j = 0; j < NJ; ++j) {
    int o = j * 16 + row;
    if (o < KOFF) {
#pragma unroll
      for (int r = 0; r < 4; ++r) {
        offs[(size_t)(px0 + kgrp * 4 + r) * KOFF + o] = acc0[j][r];
        offs[(size_t)(px0 + 16 + kgrp * 4 + r) * KOFF + o] = acc1[j][r];
      }
    }
  }
}

// ---------- deformable conv, register GEMM, pipelined, no barriers ----------
// xh: [NPIX][C] fp16; offs: [px][9][2] fp32; wf: fragment order
template <int C, int O, bool WF32, bool WH>
__global__ __launch_bounds__(64, 1)
void deform_reg_kernel(const _Float16* __restrict__ xh, const float* __restrict__ offs,
                       const _Float16* __restrict__ wf, const float* __restrict__ bd,
                       float* __restrict__ out, _Float16* __restrict__ outh) {
  constexpr int KS = C / 32;
  constexpr int NJ = O / 16;
  const int lane = threadIdx.x;
  const int row = lane & 15;
  const int kgrp = lane >> 4;
  const int ch = kgrp * 8;
  const int px0 = blockIdx.x * 32;
  const int b = px0 / HW;
  const int hw0 = px0 - b * HW;
  const int hwm0 = hw0 + row, hwm1 = hw0 + 16 + row;
  const int h0 = hwm0 / W, w0 = hwm0 - h0 * W;
  const int h1 = hwm1 / W, w1 = hwm1 - h1 * W;
  const _Float16* xb = xh + (size_t)b * HW * C;
  const float2* op = (const float2*)offs;
  const size_t ob0 = (size_t)(px0 + row) * 9;
  const size_t ob1 = (size_t)(px0 + 16 + row) * 9;

  // preload all 9 taps' offsets (kills per-tap dependent load chain)
  float2 of0[9], of1[9];
#pragma unroll
  for (int k = 0; k < 9; ++k) { of0[k] = op[ob0 + k]; of1[k] = op[ob1 + k]; }
  const float h0f = (float)(h0 - 1), w0f = (float)(w0 - 1);
  const float h1f = (float)(h1 - 1), w1f = (float)(w1 - 1);

  f32x4 acc0[NJ], acc1[NJ];
#pragma unroll
  for (int j = 0; j < NJ; ++j) {
    float bv = bd[j * 16 + row];
    acc0[j] = {bv, bv, bv, bv};
    acc1[j] = {bv, bv, bv, bv};
  }

  half8 a0[KS], a1[KS];
  {
    Corners cA = mk_corners(of0[0].x + h0f, of0[0].y + w0f);
    Corners cB = mk_corners(of1[0].x + h1f, of1[0].y + w1f);
    half8 r0[KS][4], r1[KS][4];
    load_corners<KS>(xb, ch, cA, r0);
    load_corners<KS>(xb, ch, cB, r1);
    interp_corners<KS>(cA, r0, a0);
    interp_corners<KS>(cB, r1, a1);
  }
#pragma unroll
  for (int k = 0; k < 9; ++k) {
    const _Float16* wk = wf + (size_t)k * (KS * NJ * 512);
    if (k < 8) {
      int kn = k + 1;
      float kyf = (float)(kn / 3), kxf = (float)(kn % 3);
      Corners cA = mk_corners(of0[kn].x + h0f + kyf, of0[kn].y + w0f + kxf);
      Corners cB = mk_corners(of1[kn].x + h1f + kyf, of1[kn].y + w1f + kxf);
      half8 r0[KS][4], r1[KS][4];
      load_corners<KS>(xb, ch, cA, r0);     // issue next tap's loads...
      load_corners<KS>(xb, ch, cB, r1);
      mfma_tap<KS, NJ>(wk, lane, a0, a1, acc0, acc1);  // ...MFMA current tap behind them
      interp_corners<KS>(cA, r0, a0);       // then interp next tap
      interp_corners<KS>(cB, r1, a1);
    } else {
      mfma_tap<KS, NJ>(wk, lane, a0, a1, acc0, acc1);
    }
  }
  // epilogue: D col(lane&15)=o, row((lane>>4)*4+r)=pixel-in-tile
#pragma unroll
  for (int j = 0; j < NJ; ++j) {
    int o = j * 16 + row;
#pragma unroll
    for (int r = 0; r < 4; ++r) {
      int p0 = px0 + kgrp * 4 + r;
      int p1 = p0 + 16;
      if (WF32) {
        out[((size_t)b * O + o) * HW + (p0 - b * HW)] = acc0[j][r];
        out[((size_t)b * O + o) * HW + (p1 - b * HW)] = acc1[j][r];
      }
      if (WH) {
        outh[(size_t)p0 * O + o] = (_Float16)acc0[j][r];
        outh[(size_t)p1 * O + o] = (_Float16)acc1[j][r];
      }
    }
  }
}

static inline void launch_wfrag(const float* src, _Float16* dst, int C, int Osrc, int OPAD,
                                hipStream_t stream) {
  int frags = 9 * (C / 32) * (OPAD / 16);
  hipLaunchKernelGGL(wfrag_kernel, dim3(frags), dim3(64), 0, stream, src, dst, C, Osrc, OPAD);
}

extern "C" void kernel_launch(void* const* d_in, const int* in_sizes, int n_in,
                              void* d_out, int out_size, void* d_ws, size_t ws_size,
                              hipStream_t stream) {
  const float* x1  = (const float*)d_in[0];
  const float* y   = (const float*)d_in[1];
  const float* wo1 = (const float*)d_in[2];
  const float* bo1 = (const float*)d_in[3];
  const float* wd1 = (const float*)d_in[4];
  const float* bd1 = (const float*)d_in[5];
  const float* wo2 = (const float*)d_in[6];
  const float* bo2 = (const float*)d_in[7];
  const float* wd2 = (const float*)d_in[8];
  const float* bd2 = (const float*)d_in[9];
  const float* wo3 = (const float*)d_in[10];
  const float* bo3 = (const float*)d_in[11];
  const float* wd3 = (const float*)d_in[12];
  const float* bd3 = (const float*)d_in[13];
  float* out = (float*)d_out;

  char* p = (char*)d_ws;
  auto alloc = [&](size_t bytes) {
    char* r = p;
    p += (bytes + 255) & ~(size_t)255;
    return r;
  };
  _Float16* Wo1f = (_Float16*)alloc((size_t)9 * 2 * 2 * 512 * 2);
  _Float16* Wo2f = (_Float16*)alloc((size_t)9 * 3 * 2 * 512 * 2);
  _Float16* Wo3f = (_Float16*)alloc((size_t)9 * 3 * 2 * 512 * 2);
  _Float16* W1f  = (_Float16*)alloc((size_t)9 * 2 * 6 * 512 * 2);
  _Float16* W2f  = (_Float16*)alloc((size_t)9 * 3 * 6 * 512 * 2);
  _Float16* W3f  = (_Float16*)alloc((size_t)9 * 3 * 4 * 512 * 2);
  float* offs = (float*)alloc((size_t)NPIX * KOFF * 4);   // [px][9][2]
  _Float16* x1h = (_Float16*)alloc((size_t)NPIX * 64 * 2);
  _Float16* yh  = (_Float16*)alloc((size_t)NPIX * 64 * 2);
  _Float16* h1h = (_Float16*)alloc((size_t)NPIX * 96 * 2);
  _Float16* h2h = (_Float16*)alloc((size_t)NPIX * 96 * 2);

  launch_wfrag(wo1, Wo1f, 64, 18, 32, stream);
  launch_wfrag(wo2, Wo2f, 96, 18, 32, stream);
  launch_wfrag(wo3, Wo3f, 96, 18, 32, stream);
  launch_wfrag(wd1, W1f, 64, 96, 96, stream);
  launch_wfrag(wd2, W2f, 96, 96, 96, stream);
  launch_wfrag(wd3, W3f, 96, 64, 64, stream);
  hipLaunchKernelGGL((repack_kernel<64>), dim3(NPIX / 64), dim3(256), 0, stream, x1, x1h);
  hipLaunchKernelGGL((repack_kernel<64>), dim3(NPIX / 64), dim3(256), 0, stream, y, yh);

  dim3 gw(NPIX / 32);
  dim3 wb(64);

  // stage 1: offsets from y; deform x1 -> h1h (C=64 -> O=96)
  hipLaunchKernelGGL((offset_reg_kernel<64>), gw, wb, 0, stream, yh, Wo1f, bo1, offs);
  hipLaunchKernelGGL((deform_reg_kernel<64, 96, false, true>), gw, wb, 0, stream,
                     x1h, offs, W1f, bd1, (float*)nullptr, h1h);

  // stage 2: h1 -> h2h (C=96 -> O=96)
  hipLaunchKernelGGL((offset_reg_kernel<96>), gw, wb, 0, stream, h1h, Wo2f, bo2, offs);
  hipLaunchKernelGGL((deform_reg_kernel<96, 96, false, true>), gw, wb, 0, stream,
                     h1h, offs, W2f, bd2, (float*)nullptr, h2h);

  // stage 3: h2 -> out (C=96 -> O=64)
  hipLaunchKernelGGL((offset_reg_kernel<96>), gw, wb, 0, stream, h2h, Wo3f, bo3, offs);
  hipLaunchKernelGGL((deform_reg_kernel<96, 64, true, false>), gw, wb, 0, stream,
                     h2h, offs, W3f, bd3, out, (_Float16*)nullptr);
}

// Round 7
// 131.174 us; speedup vs baseline: 9.4765x; 1.1633x over previous
//
#include <hip/hip_runtime.h>

constexpr int B = 4, H = 96, W = 96, HW = H * W;
constexpr int NPIX = B * HW;   // 36864
constexpr int KOFF = 18;       // 2*K offset channels

typedef _Float16 half8 __attribute__((ext_vector_type(8)));
typedef _Float16 half4 __attribute__((ext_vector_type(4)));
typedef float f32x4 __attribute__((ext_vector_type(4)));

__device__ __forceinline__ int iclamp(int v, int lo, int hi) {
  return v < lo ? lo : (v > hi ? hi : v);
}

struct Corners {
  int i00, i01, i10, i11;
  float w00, w01, w10, w11;
};

__device__ __forceinline__ Corners mk_corners(float py, float qx) {
  float fy = floorf(py), fx = floorf(qx);
  float wy = py - fy, wx = qx - fx;
  int y0 = (int)fy, x0 = (int)fx;
  int y1 = y0 + 1, x1 = x0 + 1;
  bool vy0 = (y0 >= 0) & (y0 < H);
  bool vy1 = (y1 >= 0) & (y1 < H);
  bool vx0 = (x0 >= 0) & (x0 < W);
  bool vx1 = (x1 >= 0) & (x1 < W);
  int r0 = iclamp(y0, 0, H - 1) * W;
  int r1 = iclamp(y1, 0, H - 1) * W;
  int c0 = iclamp(x0, 0, W - 1);
  int c1 = iclamp(x1, 0, W - 1);
  Corners cc;
  cc.i00 = r0 + c0; cc.i01 = r0 + c1; cc.i10 = r1 + c0; cc.i11 = r1 + c1;
  float a = 1.f - wy, bb = 1.f - wx;
  cc.w00 = a * bb * ((vy0 & vx0) ? 1.f : 0.f);
  cc.w01 = a * wx * ((vy0 & vx1) ? 1.f : 0.f);
  cc.w10 = wy * bb * ((vy1 & vx0) ? 1.f : 0.f);
  cc.w11 = wy * wx * ((vy1 & vx1) ? 1.f : 0.f);
  return cc;
}

// ---------- fragment helpers ----------
template <int KS>
__device__ __forceinline__ void load_corners(const _Float16* xb, int ch, const Corners& cc,
                                             half8 r[KS][4]) {
  const _Float16* p00 = xb + (size_t)cc.i00 * (KS * 32) + ch;
  const _Float16* p01 = xb + (size_t)cc.i01 * (KS * 32) + ch;
  const _Float16* p10 = xb + (size_t)cc.i10 * (KS * 32) + ch;
  const _Float16* p11 = xb + (size_t)cc.i11 * (KS * 32) + ch;
#pragma unroll
  for (int ks = 0; ks < KS; ++ks) {
    r[ks][0] = *(const half8*)(p00 + ks * 32);
    r[ks][1] = *(const half8*)(p01 + ks * 32);
    r[ks][2] = *(const half8*)(p10 + ks * 32);
    r[ks][3] = *(const half8*)(p11 + ks * 32);
  }
}

template <int KS>
__device__ __forceinline__ void interp_corners(const Corners& cc, half8 r[KS][4],
                                               half8 a[KS]) {
  _Float16 q00 = (_Float16)cc.w00, q01 = (_Float16)cc.w01;
  _Float16 q10 = (_Float16)cc.w10, q11 = (_Float16)cc.w11;
#pragma unroll
  for (int ks = 0; ks < KS; ++ks)
    a[ks] = r[ks][0] * q00 + r[ks][1] * q01 + r[ks][2] * q10 + r[ks][3] * q11;
}

template <int KS>
__device__ __forceinline__ void load_shift(const _Float16* xb, int ch, int h, int w,
                                           int ky, int kx, half8 a[KS]) {
  int yy = h + ky, xx = w + kx;
  bool v = (yy >= 0) & (yy < H) & (xx >= 0) & (xx < W);
  const _Float16* pv = xb + (size_t)(yy * W + xx) * (KS * 32) + ch;
#pragma unroll
  for (int ks = 0; ks < KS; ++ks) {
    half8 r = {0, 0, 0, 0, 0, 0, 0, 0};
    if (v) r = *(const half8*)(pv + ks * 32);
    a[ks] = r;
  }
}

template <int KS, int NJ>
__device__ __forceinline__ void mfma_tap1(const _Float16* wk, int lane,
                                          half8 a[KS], f32x4 acc[NJ]) {
#pragma unroll
  for (int ks = 0; ks < KS; ++ks)
#pragma unroll
    for (int j = 0; j < NJ; ++j) {
      half8 b = *(const half8*)(wk + ((size_t)(ks * NJ + j) * 64 + lane) * 8);
      acc[j] = __builtin_amdgcn_mfma_f32_16x16x32_f16(a[ks], b, acc[j], 0, 0, 0);
    }
}

// ---------- fused weight prep: all 6 weight sets in one launch ----------
struct WAll {
  const float* src[6];
  _Float16* dst[6];
  int C[6], Osrc[6], OPAD[6], base[6];
};

__global__ void wfrag_all_kernel(WAll wa) {
  int bid = blockIdx.x;
  int s = 0;
#pragma unroll
  for (int i = 1; i < 6; ++i) s += (bid >= wa.base[i]) ? 1 : 0;
  int fid = bid - wa.base[s];
  int C = wa.C[s], Osrc = wa.Osrc[s], OPAD = wa.OPAD[s];
  const float* wsrc = wa.src[s];
  _Float16* wf = wa.dst[s];
  int KS = C / 32;
  int NJ = OPAD / 16;
  int lane = threadIdx.x;
  int j = fid % NJ;
  int ks = (fid / NJ) % KS;
  int k = fid / (NJ * KS);
  int o = j * 16 + (lane & 15);
  int c0 = ks * 32 + (lane >> 4) * 8;
  half8 v;
#pragma unroll
  for (int u = 0; u < 8; ++u)
    v[u] = (o < Osrc) ? (_Float16)wsrc[((size_t)o * C + c0 + u) * 9 + k] : (_Float16)0.f;
  *(half8*)(wf + ((size_t)fid * 64 + lane) * 8) = v;
}

// ---------- NCHW fp32 -> NHWC fp16 repack, both inputs in one launch (C=64) ----------
__global__ __launch_bounds__(256) void repack2_kernel(const float* __restrict__ in0,
                                                      const float* __restrict__ in1,
                                                      _Float16* __restrict__ o0,
                                                      _Float16* __restrict__ o1) {
  constexpr int C = 64;
  const float* in = blockIdx.y ? in1 : in0;
  _Float16* outh = blockIdx.y ? o1 : o0;
  __shared__ float tile[64 * C];
  int t = threadIdx.x;
  int pix0 = blockIdx.x * 64;
  int b = pix0 / HW;
  int hw0 = pix0 - b * HW;
  int l = t & 63;
  for (int cc = t >> 6; cc < C; cc += 4)
    tile[cc * 64 + l] = in[((size_t)b * C + cc) * HW + hw0 + l];
  __syncthreads();
  int pl = t >> 2;
  int cq = t & 3;
  _Float16* op = outh + (size_t)(pix0 + pl) * C + cq * (C / 4);
#pragma unroll
  for (int c = 0; c < C / 4; c += 4) {
    half4 hv;
#pragma unroll
    for (int u = 0; u < 4; ++u) hv[u] = (_Float16)tile[(cq * (C / 4) + c + u) * 64 + pl];
    *(half4*)(op + c) = hv;
  }
}

// ---------- fused stage: offset conv (O pad 32) + deform conv, one wave, M=16 ----------
// xoff: offset-conv input [NPIX][C]; xdef: deform input [NPIX][C]
// wfo: offset weights frag-order (OPAD=32); wfd: deform weights frag-order (O)
template <int C, int O, bool WF32, bool WH>
__global__ __launch_bounds__(64, 2)
void stage_kernel(const _Float16* __restrict__ xoff, const _Float16* __restrict__ xdef,
                  const _Float16* __restrict__ wfo, const float* __restrict__ bo,
                  const _Float16* __restrict__ wfd, const float* __restrict__ bd,
                  float* __restrict__ out, _Float16* __restrict__ outh) {
  constexpr int KS = C / 32;
  constexpr int NJ = O / 16;
  const int lane = threadIdx.x;
  const int row = lane & 15;
  const int kgrp = lane >> 4;
  const int ch = kgrp * 8;
  const int px0 = blockIdx.x * 16;     // 16 | HW, wave never straddles batch
  const int b = px0 / HW;
  const int hw0 = px0 - b * HW;
  const int hwm = hw0 + row;
  const int h0 = hwm / W, w0 = hwm - h0 * W;
  const _Float16* xo = xoff + (size_t)b * HW * C;
  const _Float16* xd = xdef + (size_t)b * HW * C;

  __shared__ float lofs[16][KOFF];

  // ---- phase 1: offset conv GEMM (pipelined shifted-window loads) ----
  {
    f32x4 aoc[2];
#pragma unroll
    for (int j = 0; j < 2; ++j) {
      int o = j * 16 + row;
      float bv = (o < KOFF) ? bo[o] : 0.f;
      aoc[j] = {bv, bv, bv, bv};
    }
    half8 a[KS];
    load_shift<KS>(xo, ch, h0, w0, -1, -1, a);
#pragma unroll
    for (int k = 0; k < 9; ++k) {
      const _Float16* wk = wfo + (size_t)k * (KS * 2 * 512);
      if (k < 8) {
        int kn = k + 1;
        half8 n[KS];
        load_shift<KS>(xo, ch, h0, w0, kn / 3 - 1, kn % 3 - 1, n);
        mfma_tap1<KS, 2>(wk, lane, a, aoc);
#pragma unroll
        for (int ks = 0; ks < KS; ++ks) a[ks] = n[ks];
      } else {
        mfma_tap1<KS, 2>(wk, lane, a, aoc);
      }
    }
    // transpose offsets to pixel-major via LDS: D lane(row,kgrp) holds o=j*16+row,
    // pixel=px0+kgrp*4+r
#pragma unroll
    for (int j = 0; j < 2; ++j) {
      int o = j * 16 + row;
      if (o < KOFF) {
#pragma unroll
        for (int r = 0; r < 4; ++r) lofs[kgrp * 4 + r][o] = aoc[j][r];
      }
    }
  }
  __syncthreads();

  // ---- phase 2: deformable conv GEMM (pipelined bilinear gather) ----
  float2 of[9];
#pragma unroll
  for (int k = 0; k < 9; ++k) of[k] = {lofs[row][2 * k], lofs[row][2 * k + 1]};
  const float hf = (float)(h0 - 1), wwf = (float)(w0 - 1);

  f32x4 acc[NJ];
#pragma unroll
  for (int j = 0; j < NJ; ++j) {
    float bv = bd[j * 16 + row];
    acc[j] = {bv, bv, bv, bv};
  }
  half8 a[KS];
  {
    Corners cA = mk_corners(of[0].x + hf, of[0].y + wwf);
    half8 r0[KS][4];
    load_corners<KS>(xd, ch, cA, r0);
    interp_corners<KS>(cA, r0, a);
  }
#pragma unroll
  for (int k = 0; k < 9; ++k) {
    const _Float16* wk = wfd + (size_t)k * (KS * NJ * 512);
    if (k < 8) {
      int kn = k + 1;
      float kyf = (float)(kn / 3), kxf = (float)(kn % 3);
      Corners cA = mk_corners(of[kn].x + hf + kyf, of[kn].y + wwf + kxf);
      half8 r0[KS][4];
      load_corners<KS>(xd, ch, cA, r0);    // issue next tap's loads...
      mfma_tap1<KS, NJ>(wk, lane, a, acc); // ...MFMA current tap behind them
      interp_corners<KS>(cA, r0, a);       // interp next tap
    } else {
      mfma_tap1<KS, NJ>(wk, lane, a, acc);
    }
  }
  // ---- epilogue: D col(lane&15)=o, pixel=px0+kgrp*4+r ----
#pragma unroll
  for (int j = 0; j < NJ; ++j) {
    int o = j * 16 + row;
#pragma unroll
    for (int r = 0; r < 4; ++r) {
      int p = px0 + kgrp * 4 + r;
      if (WF32) out[((size_t)b * O + o) * HW + (p - b * HW)] = acc[j][r];
      if (WH) outh[(size_t)p * O + o] = (_Float16)acc[j][r];
    }
  }
}

extern "C" void kernel_launch(void* const* d_in, const int* in_sizes, int n_in,
                              void* d_out, int out_size, void* d_ws, size_t ws_size,
                              hipStream_t stream) {
  const float* x1  = (const float*)d_in[0];
  const float* y   = (const float*)d_in[1];
  const float* wo1 = (const float*)d_in[2];
  const float* bo1 = (const float*)d_in[3];
  const float* wd1 = (const float*)d_in[4];
  const float* bd1 = (const float*)d_in[5];
  const float* wo2 = (const float*)d_in[6];
  const float* bo2 = (const float*)d_in[7];
  const float* wd2 = (const float*)d_in[8];
  const float* bd2 = (const float*)d_in[9];
  const float* wo3 = (const float*)d_in[10];
  const float* bo3 = (const float*)d_in[11];
  const float* wd3 = (const float*)d_in[12];
  const float* bd3 = (const float*)d_in[13];
  float* out = (float*)d_out;

  char* p = (char*)d_ws;
  auto alloc = [&](size_t bytes) {
    char* r = p;
    p += (bytes + 255) & ~(size_t)255;
    return r;
  };
  _Float16* Wo1f = (_Float16*)alloc((size_t)9 * 2 * 2 * 512 * 2);   // 36 frags
  _Float16* Wo2f = (_Float16*)alloc((size_t)9 * 3 * 2 * 512 * 2);   // 54
  _Float16* Wo3f = (_Float16*)alloc((size_t)9 * 3 * 2 * 512 * 2);   // 54
  _Float16* W1f  = (_Float16*)alloc((size_t)9 * 2 * 6 * 512 * 2);   // 108
  _Float16* W2f  = (_Float16*)alloc((size_t)9 * 3 * 6 * 512 * 2);   // 162
  _Float16* W3f  = (_Float16*)alloc((size_t)9 * 3 * 4 * 512 * 2);   // 108
  _Float16* x1h = (_Float16*)alloc((size_t)NPIX * 64 * 2);
  _Float16* yh  = (_Float16*)alloc((size_t)NPIX * 64 * 2);
  _Float16* h1h = (_Float16*)alloc((size_t)NPIX * 96 * 2);
  _Float16* h2h = (_Float16*)alloc((size_t)NPIX * 96 * 2);

  // --- prep: one wfrag launch for all 6 weight sets ---
  WAll wa;
  wa.src[0] = wo1; wa.dst[0] = Wo1f; wa.C[0] = 64; wa.Osrc[0] = 18; wa.OPAD[0] = 32;
  wa.src[1] = wo2; wa.dst[1] = Wo2f; wa.C[1] = 96; wa.Osrc[1] = 18; wa.OPAD[1] = 32;
  wa.src[2] = wo3; wa.dst[2] = Wo3f; wa.C[2] = 96; wa.Osrc[2] = 18; wa.OPAD[2] = 32;
  wa.src[3] = wd1; wa.dst[3] = W1f;  wa.C[3] = 64; wa.Osrc[3] = 96; wa.OPAD[3] = 96;
  wa.src[4] = wd2; wa.dst[4] = W2f;  wa.C[4] = 96; wa.Osrc[4] = 96; wa.OPAD[4] = 96;
  wa.src[5] = wd3; wa.dst[5] = W3f;  wa.C[5] = 96; wa.Osrc[5] = 64; wa.OPAD[5] = 64;
  int base = 0;
  for (int i = 0; i < 6; ++i) {
    wa.base[i] = base;
    base += 9 * (wa.C[i] / 32) * (wa.OPAD[i] / 16);
  }
  hipLaunchKernelGGL(wfrag_all_kernel, dim3(base), dim3(64), 0, stream, wa);
  hipLaunchKernelGGL(repack2_kernel, dim3(NPIX / 64, 2), dim3(256), 0, stream,
                     x1, y, x1h, yh);

  dim3 gs(NPIX / 16);   // 2304 one-wave blocks -> 2.25 waves/SIMD
  dim3 wb(64);

  // stage 1: offsets from y; deform x1 -> h1h (C=64 -> O=96)
  hipLaunchKernelGGL((stage_kernel<64, 96, false, true>), gs, wb, 0, stream,
                     yh, x1h, Wo1f, bo1, W1f, bd1, (float*)nullptr, h1h);
  // stage 2: h1 -> h2h (C=96 -> O=96)
  hipLaunchKernelGGL((stage_kernel<96, 96, false, true>), gs, wb, 0, stream,
                     h1h, h1h, Wo2f, bo2, W2f, bd2, (float*)nullptr, h2h);
  // stage 3: h2 -> out (C=96 -> O=64)
  hipLaunchKernelGGL((stage_kernel<96, 64, true, false>), gs, wb, 0, stream,
                     h2h, h2h, Wo3f, bo3, W3f, bd3, out, (_Float16*)nullptr);
}